// Round 1
// baseline (1608.823 us; speedup 1.0000x reference)
//
#include <hip/hip_runtime.h>

typedef __bf16 bf16x8_t __attribute__((ext_vector_type(8)));
typedef float f32x4_t __attribute__((ext_vector_type(4)));

#define LAT_LD 1664
#define QK_DIM 576
#define V_DIM 512
#define NHEAD 16
#define TSEQ 2048
#define QLD 9216
#define YLD 8192
#define SCALE 0.044194173824159216f

__device__ __forceinline__ unsigned short f2bf(float f) {
  union { float f; unsigned int u; } v; v.f = f;
  unsigned int r = v.u + 0x7FFFu + ((v.u >> 16) & 1u);
  return (unsigned short)(r >> 16);
}
__device__ __forceinline__ float bf2f(unsigned short h) {
  union { unsigned int u; float f; } v; v.u = ((unsigned int)h) << 16;
  return v.f;
}

// ---------------- fp32 -> bf16 conversion ----------------
__global__ __launch_bounds__(256) void conv_flat(const float* __restrict__ src,
                                                 unsigned short* __restrict__ dst, int n) {
  int i = (blockIdx.x * 256 + threadIdx.x) * 4;
  if (i < n) {
    float4 v = *(const float4*)&src[i];
    ushort4 o;
    o.x = f2bf(v.x); o.y = f2bf(v.y); o.z = f2bf(v.z); o.w = f2bf(v.w);
    *(ushort4*)&dst[i] = o;
  }
}

// W_qkv [2048][1600] -> bf16 [2048][1664] zero-padded
__global__ __launch_bounds__(256) void conv_pad(const float* __restrict__ src,
                                                unsigned short* __restrict__ dst) {
  int idx = blockIdx.x * 256 + threadIdx.x;   // one ushort4 of dst; 2048*1664/4 = 851968
  if (idx >= 851968) return;
  int r = idx / 416;
  int c4 = (idx - r * 416) * 4;
  ushort4 o; o.x = 0; o.y = 0; o.z = 0; o.w = 0;
  if (c4 < 1600) {
    float4 v = *(const float4*)&src[(size_t)r * 1600 + c4];
    o.x = f2bf(v.x); o.y = f2bf(v.y); o.z = f2bf(v.z); o.w = f2bf(v.w);
  }
  *(ushort4*)&dst[(size_t)r * 1664 + c4] = o;
}

// ---------------- bf16 GEMM: C[M,N] = A[M,K] @ B[K,N] ----------------
// block = 256 threads (4 waves, 2x2), tile 128x128, BK=32, wave tile 64x64.
template <int OUTF32>
__global__ __launch_bounds__(256, 2) void gemm_bf16(
    const unsigned short* __restrict__ A, int lda,
    const unsigned short* __restrict__ B, int ldb,
    void* __restrict__ C, int ldc, int K) {
  __shared__ __align__(16) unsigned short As[128][40];
  __shared__ __align__(16) unsigned short Bs[128][40];   // Bs[n][k]

  const int tid = threadIdx.x;
  const int wave = tid >> 6, lane = tid & 63;
  const int quad = lane >> 4, l16 = lane & 15;
  const int wm = wave >> 1, wn = wave & 1;
  const int m0 = blockIdx.y * 128, n0 = blockIdx.x * 128;

  f32x4_t acc[4][4];
  f32x4_t zero = {0.f, 0.f, 0.f, 0.f};
#pragma unroll
  for (int mi = 0; mi < 4; ++mi)
#pragma unroll
    for (int ni = 0; ni < 4; ++ni) acc[mi][ni] = zero;

  for (int k0 = 0; k0 < K; k0 += 32) {
    // stage A-tile 128x32 (16B chunks)
#pragma unroll
    for (int p = 0; p < 2; ++p) {
      int idx = p * 256 + tid;
      int m = idx >> 2, c = (idx & 3) * 8;
      *(uint4*)&As[m][c] = *(const uint4*)&A[(size_t)(m0 + m) * lda + k0 + c];
    }
    // stage B-tile 32x128 transposed
#pragma unroll
    for (int p = 0; p < 2; ++p) {
      int idx = p * 256 + tid;
      int kk = idx >> 4, c = (idx & 15) * 8;
      uint4 v = *(const uint4*)&B[(size_t)(k0 + kk) * ldb + n0 + c];
      unsigned short* pv = (unsigned short*)&v;
#pragma unroll
      for (int j = 0; j < 8; ++j) Bs[c + j][kk] = pv[j];
    }
    __syncthreads();

    bf16x8_t af[4], bfr[4];
#pragma unroll
    for (int mi = 0; mi < 4; ++mi)
      af[mi] = *(const bf16x8_t*)&As[wm * 64 + mi * 16 + l16][quad * 8];
#pragma unroll
    for (int ni = 0; ni < 4; ++ni)
      bfr[ni] = *(const bf16x8_t*)&Bs[wn * 64 + ni * 16 + l16][quad * 8];
#pragma unroll
    for (int mi = 0; mi < 4; ++mi)
#pragma unroll
      for (int ni = 0; ni < 4; ++ni)
        acc[mi][ni] = __builtin_amdgcn_mfma_f32_16x16x32_bf16(af[mi], bfr[ni], acc[mi][ni], 0, 0, 0);
    __syncthreads();
  }

#pragma unroll
  for (int mi = 0; mi < 4; ++mi)
#pragma unroll
    for (int ni = 0; ni < 4; ++ni)
#pragma unroll
      for (int r = 0; r < 4; ++r) {
        int row = m0 + wm * 64 + mi * 16 + quad * 4 + r;
        int col = n0 + wn * 64 + ni * 16 + l16;
        if (OUTF32)
          ((float*)C)[(size_t)row * ldc + col] = acc[mi][ni][r];
        else
          ((unsigned short*)C)[(size_t)row * ldc + col] = f2bf(acc[mi][ni][r]);
      }
}

// ---------------- RoPE ----------------
__global__ __launch_bounds__(256) void rope_k(unsigned short* __restrict__ lat,
                                              const float* __restrict__ cosb,
                                              const float* __restrict__ sinb) {
  int idx = blockIdx.x * 256 + threadIdx.x;   // t*32 + d, total 65536
  if (idx >= TSEQ * 32) return;
  int t = idx >> 5, d = idx & 31;
  unsigned short* p = &lat[(size_t)t * LAT_LD + 512];
  float x1 = bf2f(p[d]), x2 = bf2f(p[d + 32]);
  float c0 = cosb[t * 64 + d], s0 = sinb[t * 64 + d];
  float c1 = cosb[t * 64 + d + 32], s1 = sinb[t * 64 + d + 32];
  p[d] = f2bf(x1 * c0 - x2 * s0);
  p[d + 32] = f2bf(x2 * c1 + x1 * s1);
}

__global__ __launch_bounds__(256) void rope_q(unsigned short* __restrict__ q,
                                              const float* __restrict__ cosb,
                                              const float* __restrict__ sinb) {
  int idx = blockIdx.x * 256 + threadIdx.x;   // t*512 + h*32 + d, total 1048576
  if (idx >= TSEQ * NHEAD * 32) return;
  int t = idx >> 9, h = (idx >> 5) & 15, d = idx & 31;
  unsigned short* p = &q[(size_t)t * QLD + h * QK_DIM + 512];
  float x1 = bf2f(p[d]), x2 = bf2f(p[d + 32]);
  float c0 = cosb[t * 64 + d], s0 = sinb[t * 64 + d];
  float c1 = cosb[t * 64 + d + 32], s1 = sinb[t * 64 + d + 32];
  p[d] = f2bf(x1 * c0 - x2 * s0);
  p[d + 32] = f2bf(x2 * c1 + x1 * s1);
}

// ---------------- causal attention (flash-style, no running max) ----------------
// block = 256 thr (4 waves). Each block: one head h, 64 q-rows. Wave w: 16 q-rows.
// K-tiles of 32 keys. exp() without max subtraction (scores bounded ~|15|).
#define KPAD 584
__global__ __launch_bounds__(256, 1) void attn_kernel(
    const unsigned short* __restrict__ lat,    // [2048][1664]; k = cols 0..575 (512..575 roped), v = cols 0..511
    const unsigned short* __restrict__ qbuf,   // [2048][9216] roped
    unsigned short* __restrict__ ybuf) {       // [2048][8192]
  __shared__ __align__(16) unsigned short Qs[64][KPAD];
  __shared__ __align__(16) unsigned short Ks[32][KPAD];
  __shared__ __align__(16) unsigned short Vt[512][40];   // [feature][key]
  __shared__ __align__(16) unsigned short Es[4][16][40]; // per-wave P tile

  const int h = blockIdx.x & 15;
  const int qb = 31 - (blockIdx.x >> 4);      // heavy blocks first
  const int tid = threadIdx.x;
  const int wave = tid >> 6, lane = tid & 63;
  const int quad = lane >> 4, l16 = lane & 15;
  const int q0 = qb * 64;

  // stage Q tile: 64 x 576
  for (int it = tid; it < 64 * 72; it += 256) {
    int r = it / 72, c = (it - r * 72) * 8;
    *(uint4*)&Qs[r][c] = *(const uint4*)&qbuf[(size_t)(q0 + r) * QLD + h * QK_DIM + c];
  }

  f32x4_t acc_o[32];
  f32x4_t zero = {0.f, 0.f, 0.f, 0.f};
#pragma unroll
  for (int n = 0; n < 32; ++n) acc_o[n] = zero;
  float lsum[4] = {0.f, 0.f, 0.f, 0.f};

  const int nkt = (q0 + 64) >> 5;
  for (int kt = 0; kt < nkt; ++kt) {
    const int k0 = kt * 32;
    if (kt) __syncthreads();   // protect Ks/Vt from overwrite
    // stage K tile 32 x 576
    for (int it = tid; it < 32 * 72; it += 256) {
      int r = it / 72, c = (it - r * 72) * 8;
      *(uint4*)&Ks[r][c] = *(const uint4*)&lat[(size_t)(k0 + r) * LAT_LD + c];
    }
    // stage V transposed: Vt[feature][key], V = lat[:, :512]
    for (int it = tid; it < 32 * 64; it += 256) {
      int r = it >> 6, c = (it & 63) * 8;
      uint4 v = *(const uint4*)&lat[(size_t)(k0 + r) * LAT_LD + c];
      unsigned short* pv = (unsigned short*)&v;
#pragma unroll
      for (int j = 0; j < 8; ++j) Vt[c + j][r] = pv[j];
    }
    __syncthreads();

    // S = Q K^T  (16 rows x 32 keys per wave)
    f32x4_t sacc[2];
    sacc[0] = zero; sacc[1] = zero;
#pragma unroll
    for (int kc = 0; kc < 18; ++kc) {
      bf16x8_t a = *(const bf16x8_t*)&Qs[wave * 16 + l16][kc * 32 + quad * 8];
#pragma unroll
      for (int nt = 0; nt < 2; ++nt) {
        bf16x8_t b = *(const bf16x8_t*)&Ks[nt * 16 + l16][kc * 32 + quad * 8];
        sacc[nt] = __builtin_amdgcn_mfma_f32_16x16x32_bf16(a, b, sacc[nt], 0, 0, 0);
      }
    }

    // exp + causal mask, accumulate row sums, write E (bf16) to LDS
#pragma unroll
    for (int nt = 0; nt < 2; ++nt)
#pragma unroll
      for (int r = 0; r < 4; ++r) {
        int qrow = q0 + wave * 16 + quad * 4 + r;
        int key = k0 + nt * 16 + l16;
        float ev = 0.f;
        if (key <= qrow) ev = __expf(sacc[nt][r] * SCALE);
        lsum[r] += ev;
        Es[wave][quad * 4 + r][nt * 16 + l16] = f2bf(ev);
      }
    __syncthreads();

    // O += E @ V
    bf16x8_t ea = *(const bf16x8_t*)&Es[wave][l16][quad * 8];
#pragma unroll
    for (int n = 0; n < 32; ++n) {
      bf16x8_t b = *(const bf16x8_t*)&Vt[n * 16 + l16][quad * 8];
      acc_o[n] = __builtin_amdgcn_mfma_f32_16x16x32_bf16(ea, b, acc_o[n], 0, 0, 0);
    }
  }

  // reduce row sums across the 16 lanes of each quad
  float inv[4];
#pragma unroll
  for (int r = 0; r < 4; ++r) {
    float s = lsum[r];
#pragma unroll
    for (int off = 1; off < 16; off <<= 1) s += __shfl_xor(s, off, 64);
    inv[r] = 1.f / s;
  }

#pragma unroll
  for (int n = 0; n < 32; ++n)
#pragma unroll
    for (int r = 0; r < 4; ++r) {
      int row = q0 + wave * 16 + quad * 4 + r;
      int col = h * V_DIM + n * 16 + l16;
      ybuf[(size_t)row * YLD + col] = f2bf(acc_o[n][r] * inv[r]);
    }
}

// ---------------- launch ----------------
extern "C" void kernel_launch(void* const* d_in, const int* in_sizes, int n_in,
                              void* d_out, int out_size, void* d_ws, size_t ws_size,
                              hipStream_t stream) {
  (void)in_sizes; (void)n_in; (void)out_size; (void)ws_size;
  const float* x     = (const float*)d_in[0];
  const float* cosb  = (const float*)d_in[1];
  const float* sinb  = (const float*)d_in[2];
  const float* wqkv  = (const float*)d_in[3];
  const float* wqdec = (const float*)d_in[4];
  const float* wout  = (const float*)d_in[5];
  float* out = (float*)d_out;

  unsigned short* ws     = (unsigned short*)d_ws;
  unsigned short* xb     = ws;                                  // 2048*2048
  unsigned short* wqkvb  = xb     + (size_t)2048 * 2048;        // 2048*1664
  unsigned short* wqdecb = wqkvb  + (size_t)2048 * 1664;        // 1024*9216
  unsigned short* woutb  = wqdecb + (size_t)1024 * 9216;        // 8192*2048
  unsigned short* lat    = woutb  + (size_t)8192 * 2048;        // 2048*1664
  unsigned short* qbuf   = lat    + (size_t)2048 * 1664;        // 2048*9216
  unsigned short* ybuf   = qbuf   + (size_t)2048 * 9216;        // 2048*8192
  // total ws use: ~146 MB

  conv_flat<<<4096, 256, 0, stream>>>(x, xb, 2048 * 2048);
  conv_pad<<<3328, 256, 0, stream>>>(wqkv, wqkvb);
  conv_flat<<<9216, 256, 0, stream>>>(wqdec, wqdecb, 1024 * 9216);
  conv_flat<<<16384, 256, 0, stream>>>(wout, woutb, 8192 * 2048);

  // latents = x @ W_qkv    [2048,2048]x[2048,1664->pad] -> bf16 [2048][1664]
  gemm_bf16<0><<<dim3(13, 16), 256, 0, stream>>>(xb, 2048, wqkvb, 1664, lat, LAT_LD, 2048);
  rope_k<<<256, 256, 0, stream>>>(lat, cosb, sinb);

  // q = c_q @ W_qdec       [2048,1024]x[1024,9216] -> bf16 [2048][9216]
  gemm_bf16<0><<<dim3(72, 16), 256, 0, stream>>>(lat + 576, LAT_LD, wqdecb, 9216, qbuf, QLD, 1024);
  rope_q<<<4096, 256, 0, stream>>>(qbuf, cosb, sinb);

  // attention -> y bf16 [2048][8192]
  attn_kernel<<<512, 256, 0, stream>>>(lat, qbuf, ybuf);

  // out = y @ W_out        [2048,8192]x[8192,2048] -> fp32 d_out
  gemm_bf16<1><<<dim3(16, 16), 256, 0, stream>>>(ybuf, YLD, woutb, 2048, out, 2048, 8192);
}

// Round 2
// 730.024 us; speedup vs baseline: 2.2038x; 2.2038x over previous
//
#include <hip/hip_runtime.h>

typedef __bf16 bf16x8_t __attribute__((ext_vector_type(8)));
typedef float f32x4_t __attribute__((ext_vector_type(4)));

#define LAT_LD 1664
#define QK_DIM 576
#define V_DIM 512
#define NHEAD 16
#define TSEQ 2048
#define QLD 9216
#define YLD 8192
#define SCALE 0.044194173824159216f

__device__ __forceinline__ unsigned short f2bf(float f) {
  union { float f; unsigned int u; } v; v.f = f;
  unsigned int r = v.u + 0x7FFFu + ((v.u >> 16) & 1u);
  return (unsigned short)(r >> 16);
}

// ---------------- fp32 -> bf16 flat conversion (x) ----------------
__global__ __launch_bounds__(256) void conv_flat(const float* __restrict__ src,
                                                 unsigned short* __restrict__ dst, int n) {
  int i = (blockIdx.x * 256 + threadIdx.x) * 4;
  if (i < n) {
    float4 v = *(const float4*)&src[i];
    ushort4 o;
    o.x = f2bf(v.x); o.y = f2bf(v.y); o.z = f2bf(v.z); o.w = f2bf(v.w);
    *(ushort4*)&dst[i] = o;
  }
}

// ---------------- fp32 -> bf16 transpose-convert (weights) ----------------
// in: fp32 [R][Csrc]; out: bf16 [Cpad][R] with rows >= Csrc zeroed.
// grid: (R/64, Cpad/64), 256 threads.
__global__ __launch_bounds__(256) void conv_t(const float* __restrict__ src, int R, int Csrc,
                                              unsigned short* __restrict__ dst) {
  __shared__ unsigned short T[64][72];
  const int tid = threadIdx.x;
  const int r0 = blockIdx.x * 64, c0 = blockIdx.y * 64;
  const bool live = (c0 < Csrc);
#pragma unroll
  for (int it = 0; it < 4; ++it) {
    int idx = it * 256 + tid;
    int c4 = (idx >> 6) * 4;    // 0..60
    int r = idx & 63;
    float4 v = {0.f, 0.f, 0.f, 0.f};
    if (live) v = *(const float4*)&src[(size_t)(r0 + r) * Csrc + c0 + c4];
    T[c4 + 0][r] = f2bf(v.x);
    T[c4 + 1][r] = f2bf(v.y);
    T[c4 + 2][r] = f2bf(v.z);
    T[c4 + 3][r] = f2bf(v.w);
  }
  __syncthreads();
#pragma unroll
  for (int it = 0; it < 2; ++it) {
    int idx = it * 256 + tid;
    int cc = idx >> 3, r8 = (idx & 7) * 8;
    uint4 v = *(const uint4*)&T[cc][r8];
    *(uint4*)&dst[(size_t)(c0 + cc) * R + r0 + r8] = v;
  }
}

// ---------------- bf16 transpose: lat[:, 0:512] -> vtg[512][2048] ----------------
// grid: (2048/64, 512/64) = (32, 8), 256 threads.
__global__ __launch_bounds__(256) void vtrans(const unsigned short* __restrict__ lat,
                                              unsigned short* __restrict__ vtg) {
  __shared__ unsigned short T[64][72];
  const int tid = threadIdx.x;
  const int r0 = blockIdx.x * 64, c0 = blockIdx.y * 64;
#pragma unroll
  for (int it = 0; it < 2; ++it) {
    int idx = it * 256 + tid;
    int c8 = (idx >> 6) * 8;    // 0..56
    int r = idx & 63;
    uint4 v = *(const uint4*)&lat[(size_t)(r0 + r) * LAT_LD + c0 + c8];
    unsigned short* pv = (unsigned short*)&v;
#pragma unroll
    for (int j = 0; j < 8; ++j) T[c8 + j][r] = pv[j];
  }
  __syncthreads();
#pragma unroll
  for (int it = 0; it < 2; ++it) {
    int idx = it * 256 + tid;
    int cc = idx >> 3, r8 = (idx & 7) * 8;
    uint4 v = *(const uint4*)&T[cc][r8];
    *(uint4*)&vtg[(size_t)(c0 + cc) * TSEQ + r0 + r8] = v;
  }
}

// ---------------- bf16 GEMM (B transposed): C[M,N] = A[M,K] @ Bt[N,K]^T ----------------
// 256 threads (4 waves, 2x2), tile 128x128, BK=32, wave tile 64x64.
template <int OUTF32>
__global__ __launch_bounds__(256, 2) void gemm_bt(
    const unsigned short* __restrict__ A, int lda,
    const unsigned short* __restrict__ Bt, int ldb,
    void* __restrict__ C, int ldc, int K) {
  __shared__ __align__(16) unsigned short As[128][40];
  __shared__ __align__(16) unsigned short Bs[128][40];

  const int tid = threadIdx.x;
  const int wave = tid >> 6, lane = tid & 63;
  const int quad = lane >> 4, l16 = lane & 15;
  const int wm = wave >> 1, wn = wave & 1;
  const int m0 = blockIdx.y * 128, n0 = blockIdx.x * 128;

  f32x4_t acc[4][4];
  f32x4_t zero = {0.f, 0.f, 0.f, 0.f};
#pragma unroll
  for (int mi = 0; mi < 4; ++mi)
#pragma unroll
    for (int ni = 0; ni < 4; ++ni) acc[mi][ni] = zero;

  for (int k0 = 0; k0 < K; k0 += 32) {
#pragma unroll
    for (int p = 0; p < 2; ++p) {
      int idx = p * 256 + tid;
      int m = idx >> 2, c = (idx & 3) * 8;
      *(uint4*)&As[m][c] = *(const uint4*)&A[(size_t)(m0 + m) * lda + k0 + c];
      *(uint4*)&Bs[m][c] = *(const uint4*)&Bt[(size_t)(n0 + m) * ldb + k0 + c];
    }
    __syncthreads();

    bf16x8_t af[4], bfr[4];
#pragma unroll
    for (int mi = 0; mi < 4; ++mi)
      af[mi] = *(const bf16x8_t*)&As[wm * 64 + mi * 16 + l16][quad * 8];
#pragma unroll
    for (int ni = 0; ni < 4; ++ni)
      bfr[ni] = *(const bf16x8_t*)&Bs[wn * 64 + ni * 16 + l16][quad * 8];
#pragma unroll
    for (int mi = 0; mi < 4; ++mi)
#pragma unroll
      for (int ni = 0; ni < 4; ++ni)
        acc[mi][ni] = __builtin_amdgcn_mfma_f32_16x16x32_bf16(af[mi], bfr[ni], acc[mi][ni], 0, 0, 0);
    __syncthreads();
  }

#pragma unroll
  for (int mi = 0; mi < 4; ++mi)
#pragma unroll
    for (int ni = 0; ni < 4; ++ni)
#pragma unroll
      for (int r = 0; r < 4; ++r) {
        int row = m0 + wm * 64 + mi * 16 + quad * 4 + r;
        int col = n0 + wn * 64 + ni * 16 + l16;
        if (OUTF32)
          ((float*)C)[(size_t)row * ldc + col] = acc[mi][ni][r];
        else
          ((unsigned short*)C)[(size_t)row * ldc + col] = f2bf(acc[mi][ni][r]);
      }
}

// ---------------- RoPE ----------------
__global__ __launch_bounds__(256) void rope_k(unsigned short* __restrict__ lat,
                                              const float* __restrict__ cosb,
                                              const float* __restrict__ sinb) {
  int idx = blockIdx.x * 256 + threadIdx.x;
  if (idx >= TSEQ * 32) return;
  int t = idx >> 5, d = idx & 31;
  unsigned short* p = &lat[(size_t)t * LAT_LD + 512];
  union { unsigned int u; float f; } a, b;
  a.u = ((unsigned int)p[d]) << 16; b.u = ((unsigned int)p[d + 32]) << 16;
  float c0 = cosb[t * 64 + d], s0 = sinb[t * 64 + d];
  float c1 = cosb[t * 64 + d + 32], s1 = sinb[t * 64 + d + 32];
  p[d] = f2bf(a.f * c0 - b.f * s0);
  p[d + 32] = f2bf(b.f * c1 + a.f * s1);
}

__global__ __launch_bounds__(256) void rope_q(unsigned short* __restrict__ q,
                                              const float* __restrict__ cosb,
                                              const float* __restrict__ sinb) {
  int idx = blockIdx.x * 256 + threadIdx.x;
  if (idx >= TSEQ * NHEAD * 32) return;
  int t = idx >> 9, h = (idx >> 5) & 15, d = idx & 31;
  unsigned short* p = &q[(size_t)t * QLD + h * QK_DIM + 512];
  union { unsigned int u; float f; } a, b;
  a.u = ((unsigned int)p[d]) << 16; b.u = ((unsigned int)p[d + 32]) << 16;
  float c0 = cosb[t * 64 + d], s0 = sinb[t * 64 + d];
  float c1 = cosb[t * 64 + d + 32], s1 = sinb[t * 64 + d + 32];
  p[d] = f2bf(a.f * c0 - b.f * s0);
  p[d + 32] = f2bf(b.f * c1 + a.f * s1);
}

// ---------------- causal attention ----------------
// 512 threads (8 waves). Block b: head h = b&15, pair p = b>>4.
// Waves 0-3: q-tile (31-p)*64 (heavy); waves 4-7: q-tile p*64 (light).
// Uniform total work per block. Q fragments in registers; K row-major LDS;
// V pre-transposed globally (vtg) -> conflict-free b128 LDS staging.
#define KSLD 584
#define VTLD 40
__global__ __launch_bounds__(512, 2) void attn_kernel(
    const unsigned short* __restrict__ lat,     // [2048][1664] K = cols 0..575
    const unsigned short* __restrict__ vtg,     // [512][2048]  V^T
    const unsigned short* __restrict__ qbuf,    // [2048][9216] roped
    unsigned short* __restrict__ ybuf) {        // [2048][8192]
  __shared__ __align__(16) unsigned short Ks[32][KSLD];
  __shared__ __align__(16) unsigned short Vt[512][VTLD];
  __shared__ __align__(16) unsigned short Es[8][16][VTLD];

  const int h = blockIdx.x & 15;
  const int p = blockIdx.x >> 4;
  const int tid = threadIdx.x;
  const int wave = tid >> 6, lane = tid & 63;
  const int quad = lane >> 4, l16 = lane & 15;

  const int q0 = (wave < 4) ? (31 - p) * 64 : p * 64;
  const int myKT = (q0 >> 5) + 2;
  const int KT = 64 - 2 * p;          // max over the two chunks

  // Q fragments -> registers (18 x bf16x8 = 72 VGPRs)
  const int qsub = (wave & 3) * 16;
  bf16x8_t qf[18];
  {
    const unsigned short* qp = &qbuf[(size_t)(q0 + qsub + l16) * QLD + h * QK_DIM + quad * 8];
#pragma unroll
    for (int kc = 0; kc < 18; ++kc) qf[kc] = *(const bf16x8_t*)&qp[kc * 32];
  }

  f32x4_t acc_o[32];
  f32x4_t zero = {0.f, 0.f, 0.f, 0.f};
#pragma unroll
  for (int n = 0; n < 32; ++n) acc_o[n] = zero;
  float lsum[4] = {0.f, 0.f, 0.f, 0.f};

  for (int kt = 0; kt < KT; ++kt) {
    const int k0 = kt * 32;
    if (kt) __syncthreads();
    // stage K tile 32x576 (b128, conflict-free)
    for (int it = tid; it < 2304; it += 512) {
      int r = it / 72, c = (it - r * 72) * 8;
      *(uint4*)&Ks[r][c] = *(const uint4*)&lat[(size_t)(k0 + r) * LAT_LD + c];
    }
    // stage V^T tile 512x32 from vtg (b128, conflict-free)
    {
      int idx = tid;
#pragma unroll
      for (int it = 0; it < 4; ++it, idx += 512) {
        int f = idx >> 2, c8 = (idx & 3) * 8;
        *(uint4*)&Vt[f][c8] = *(const uint4*)&vtg[(size_t)f * TSEQ + k0 + c8];
      }
    }
    __syncthreads();

    if (kt < myKT) {
      // S = Q K^T : 16 q-rows x 32 keys
      f32x4_t sacc[2];
      sacc[0] = zero; sacc[1] = zero;
#pragma unroll
      for (int kc = 0; kc < 18; ++kc) {
#pragma unroll
        for (int nt = 0; nt < 2; ++nt) {
          bf16x8_t b = *(const bf16x8_t*)&Ks[nt * 16 + l16][kc * 32 + quad * 8];
          sacc[nt] = __builtin_amdgcn_mfma_f32_16x16x32_bf16(qf[kc], b, sacc[nt], 0, 0, 0);
        }
      }
      // mask + exp -> Es (per-wave private, no barrier needed)
#pragma unroll
      for (int nt = 0; nt < 2; ++nt)
#pragma unroll
        for (int r = 0; r < 4; ++r) {
          int qr = q0 + qsub + quad * 4 + r;
          int key = k0 + nt * 16 + l16;
          float ev = (key <= qr) ? __expf(sacc[nt][r] * SCALE) : 0.f;
          lsum[r] += ev;
          Es[wave][quad * 4 + r][nt * 16 + l16] = f2bf(ev);
        }
      // O += E @ V
      bf16x8_t ea = *(const bf16x8_t*)&Es[wave][l16][quad * 8];
#pragma unroll
      for (int n = 0; n < 32; ++n) {
        bf16x8_t b = *(const bf16x8_t*)&Vt[n * 16 + l16][quad * 8];
        acc_o[n] = __builtin_amdgcn_mfma_f32_16x16x32_bf16(ea, b, acc_o[n], 0, 0, 0);
      }
    }
  }

  // per-q-row softmax denominators: reduce over the 16 lanes of each quad
  float inv[4];
#pragma unroll
  for (int r = 0; r < 4; ++r) {
    float s = lsum[r];
#pragma unroll
    for (int off = 1; off < 16; off <<= 1) s += __shfl_xor(s, off, 64);
    inv[r] = 1.f / s;
  }

#pragma unroll
  for (int n = 0; n < 32; ++n)
#pragma unroll
    for (int r = 0; r < 4; ++r) {
      int row = q0 + qsub + quad * 4 + r;
      int col = h * V_DIM + n * 16 + l16;
      ybuf[(size_t)row * YLD + col] = f2bf(acc_o[n][r] * inv[r]);
    }
}

// ---------------- launch ----------------
extern "C" void kernel_launch(void* const* d_in, const int* in_sizes, int n_in,
                              void* d_out, int out_size, void* d_ws, size_t ws_size,
                              hipStream_t stream) {
  (void)in_sizes; (void)n_in; (void)out_size; (void)ws_size;
  const float* x     = (const float*)d_in[0];
  const float* cosb  = (const float*)d_in[1];
  const float* sinb  = (const float*)d_in[2];
  const float* wqkv  = (const float*)d_in[3];
  const float* wqdec = (const float*)d_in[4];
  const float* wout  = (const float*)d_in[5];
  float* out = (float*)d_out;

  unsigned short* ws     = (unsigned short*)d_ws;
  unsigned short* xb     = ws;                                  // 2048*2048
  unsigned short* wqkvT  = xb     + (size_t)2048 * 2048;        // 1664*2048 (rows 1600+ zero)
  unsigned short* wqdecT = wqkvT  + (size_t)1664 * 2048;        // 9216*1024
  unsigned short* woutT  = wqdecT + (size_t)9216 * 1024;        // 2048*8192
  unsigned short* lat    = woutT  + (size_t)2048 * 8192;        // 2048*1664
  unsigned short* qbuf   = lat    + (size_t)2048 * 1664;        // 2048*9216
  unsigned short* ybuf   = qbuf   + (size_t)2048 * 9216;        // 2048*8192
  unsigned short* vtg    = ybuf   + (size_t)2048 * 8192;        // 512*2048

  conv_flat<<<4096, 256, 0, stream>>>(x, xb, 2048 * 2048);
  conv_t<<<dim3(32, 26), 256, 0, stream>>>(wqkv, 2048, 1600, wqkvT);
  conv_t<<<dim3(16, 144), 256, 0, stream>>>(wqdec, 1024, 9216, wqdecT);
  conv_t<<<dim3(128, 32), 256, 0, stream>>>(wout, 8192, 2048, woutT);

  // latents = x @ W_qkv   -> bf16 [2048][1664]
  gemm_bt<0><<<dim3(13, 16), 256, 0, stream>>>(xb, 2048, wqkvT, 2048, lat, LAT_LD, 2048);
  rope_k<<<256, 256, 0, stream>>>(lat, cosb, sinb);
  vtrans<<<dim3(32, 8), 256, 0, stream>>>(lat, vtg);

  // q = c_q @ W_qdec      -> bf16 [2048][9216]
  gemm_bt<0><<<dim3(72, 16), 256, 0, stream>>>(lat + 576, LAT_LD, wqdecT, 1024, qbuf, QLD, 1024);
  rope_q<<<4096, 256, 0, stream>>>(qbuf, cosb, sinb);

  // attention -> y bf16 [2048][8192]
  attn_kernel<<<256, 512, 0, stream>>>(lat, vtg, qbuf, ybuf);

  // out = y @ W_out       -> fp32 d_out
  gemm_bt<1><<<dim3(16, 16), 256, 0, stream>>>(ybuf, YLD, woutT, 8192, out, 2048, 8192);
}

// Round 3
// 658.729 us; speedup vs baseline: 2.4423x; 1.1082x over previous
//
#include <hip/hip_runtime.h>

typedef __bf16 bf16x8_t __attribute__((ext_vector_type(8)));
typedef float f32x4_t __attribute__((ext_vector_type(4)));

#define LAT_LD 1664
#define QK_DIM 576
#define V_DIM 512
#define NHEAD 16
#define TSEQ 2048
#define QLD 9216
#define YLD 8192
#define SCALE 0.044194173824159216f

__device__ __forceinline__ unsigned short f2bf(float f) {
  union { float f; unsigned int u; } v; v.f = f;
  unsigned int r = v.u + 0x7FFFu + ((v.u >> 16) & 1u);
  return (unsigned short)(r >> 16);
}

// async global->LDS 16B (m97 pattern). LDS dest must be wave-uniform base + lane*16.
__device__ __forceinline__ void load_lds16(const unsigned short* g, unsigned short* l) {
  __builtin_amdgcn_global_load_lds((const __attribute__((address_space(1))) void*)g,
                                   (__attribute__((address_space(3))) void*)l, 16, 0, 0);
}

// ---------------- fp32 -> bf16 flat conversion (x) ----------------
__global__ __launch_bounds__(256) void conv_flat(const float* __restrict__ src,
                                                 unsigned short* __restrict__ dst, int n) {
  int i = (blockIdx.x * 256 + threadIdx.x) * 4;
  if (i < n) {
    float4 v = *(const float4*)&src[i];
    ushort4 o;
    o.x = f2bf(v.x); o.y = f2bf(v.y); o.z = f2bf(v.z); o.w = f2bf(v.w);
    *(ushort4*)&dst[i] = o;
  }
}

// ---------------- fp32 -> bf16 transpose-convert (weights) ----------------
__global__ __launch_bounds__(256) void conv_t(const float* __restrict__ src, int R, int Csrc,
                                              unsigned short* __restrict__ dst) {
  __shared__ unsigned short T[64][72];
  const int tid = threadIdx.x;
  const int r0 = blockIdx.x * 64, c0 = blockIdx.y * 64;
  const bool live = (c0 < Csrc);
#pragma unroll
  for (int it = 0; it < 4; ++it) {
    int idx = it * 256 + tid;
    int c4 = (idx >> 6) * 4;
    int r = idx & 63;
    float4 v = {0.f, 0.f, 0.f, 0.f};
    if (live) v = *(const float4*)&src[(size_t)(r0 + r) * Csrc + c0 + c4];
    T[c4 + 0][r] = f2bf(v.x);
    T[c4 + 1][r] = f2bf(v.y);
    T[c4 + 2][r] = f2bf(v.z);
    T[c4 + 3][r] = f2bf(v.w);
  }
  __syncthreads();
#pragma unroll
  for (int it = 0; it < 2; ++it) {
    int idx = it * 256 + tid;
    int cc = idx >> 3, r8 = (idx & 7) * 8;
    uint4 v = *(const uint4*)&T[cc][r8];
    *(uint4*)&dst[(size_t)(c0 + cc) * R + r0 + r8] = v;
  }
}

// ---------------- bf16 transpose: lat[:, 0:512] -> vtg[512][2048] ----------------
__global__ __launch_bounds__(256) void vtrans(const unsigned short* __restrict__ lat,
                                              unsigned short* __restrict__ vtg) {
  __shared__ unsigned short T[64][72];
  const int tid = threadIdx.x;
  const int r0 = blockIdx.x * 64, c0 = blockIdx.y * 64;
#pragma unroll
  for (int it = 0; it < 2; ++it) {
    int idx = it * 256 + tid;
    int c8 = (idx >> 6) * 8;
    int r = idx & 63;
    uint4 v = *(const uint4*)&lat[(size_t)(r0 + r) * LAT_LD + c0 + c8];
    unsigned short* pv = (unsigned short*)&v;
#pragma unroll
    for (int j = 0; j < 8; ++j) T[c8 + j][r] = pv[j];
  }
  __syncthreads();
#pragma unroll
  for (int it = 0; it < 2; ++it) {
    int idx = it * 256 + tid;
    int cc = idx >> 3, r8 = (idx & 7) * 8;
    uint4 v = *(const uint4*)&T[cc][r8];
    *(uint4*)&vtg[(size_t)(c0 + cc) * TSEQ + r0 + r8] = v;
  }
}

// ---------------- m97-style GEMM core (macros for the shared body) ----------------
// 256 thr (4 waves 2x2), tile 128x128, BK=32, unpadded LDS + global_load_lds x16.
#define GEMM_PROLOGUE()                                                     \
  __shared__ __align__(16) unsigned short As[4096];                         \
  __shared__ __align__(16) unsigned short Bs[4096];                         \
  const int tid = threadIdx.x;                                              \
  const int wave = tid >> 6, lane = tid & 63;                               \
  const int quad = lane >> 4, l16 = lane & 15;                              \
  const int wm = wave >> 1, wn = wave & 1;                                  \
  f32x4_t acc[4][4];                                                        \
  f32x4_t zero = {0.f, 0.f, 0.f, 0.f};                                      \
  _Pragma("unroll") for (int mi = 0; mi < 4; ++mi)                          \
    _Pragma("unroll") for (int ni = 0; ni < 4; ++ni) acc[mi][ni] = zero;

#define GEMM_KLOOP(Aptr, Alda, Bptr, Bldb, M0, N0, KLEN)                    \
  for (int k0 = 0; k0 < (KLEN); k0 += 32) {                                 \
    _Pragma("unroll") for (int p2 = 0; p2 < 2; ++p2) {                      \
      int ci = p2 * 256 + tid;                                              \
      int rr2 = ci >> 2, cc2 = (ci & 3) * 8;                                \
      load_lds16(&(Aptr)[(size_t)((M0) + rr2) * (Alda) + k0 + cc2], &As[ci * 8]); \
      load_lds16(&(Bptr)[(size_t)((N0) + rr2) * (Bldb) + k0 + cc2], &Bs[ci * 8]); \
    }                                                                       \
    __syncthreads();                                                        \
    bf16x8_t af[4], bfr[4];                                                 \
    _Pragma("unroll") for (int mi = 0; mi < 4; ++mi)                        \
      af[mi] = *(const bf16x8_t*)&As[(wm * 64 + mi * 16 + l16) * 32 + quad * 8]; \
    _Pragma("unroll") for (int ni = 0; ni < 4; ++ni)                        \
      bfr[ni] = *(const bf16x8_t*)&Bs[(wn * 64 + ni * 16 + l16) * 32 + quad * 8]; \
    _Pragma("unroll") for (int mi = 0; mi < 4; ++mi)                        \
      _Pragma("unroll") for (int ni = 0; ni < 4; ++ni)                      \
        acc[mi][ni] = __builtin_amdgcn_mfma_f32_16x16x32_bf16(af[mi], bfr[ni], acc[mi][ni], 0, 0, 0); \
    __syncthreads();                                                        \
  }

// ---------------- plain GEMM: C[M,N] = A[M,K] @ Bt[N,K]^T ----------------
template <int OUTF32>
__global__ __launch_bounds__(256, 2) void gemm_bt(
    const unsigned short* __restrict__ A, int lda,
    const unsigned short* __restrict__ Bt, int ldb,
    void* __restrict__ C, int ldc, int K) {
  const int m0 = blockIdx.y * 128, n0 = blockIdx.x * 128;
  GEMM_PROLOGUE();
  GEMM_KLOOP(A, lda, Bt, ldb, m0, n0, K);
#pragma unroll
  for (int mi = 0; mi < 4; ++mi)
#pragma unroll
    for (int ni = 0; ni < 4; ++ni)
#pragma unroll
      for (int r = 0; r < 4; ++r) {
        int row = m0 + wm * 64 + mi * 16 + quad * 4 + r;
        int col = n0 + wn * 64 + ni * 16 + l16;
        if (OUTF32)
          ((float*)C)[(size_t)row * ldc + col] = acc[mi][ni][r];
        else
          ((unsigned short*)C)[(size_t)row * ldc + col] = f2bf(acc[mi][ni][r]);
      }
}

// ---------------- QK^T + exp pass (causal-tiled), panel of 512 q-rows ----------------
// grid: (tiles_per_head = 16*panel+10, 16 heads). Writes E[h][512][Kp] bf16, rowsums fp32.
__global__ __launch_bounds__(256, 2) void qke_kernel(
    const unsigned short* __restrict__ qbuf,
    const unsigned short* __restrict__ lat,
    unsigned short* __restrict__ Ebuf,
    float* __restrict__ lsum, int panel) {
  int tx = blockIdx.x, i_l = 0, cnt = 4 * panel + 1;
  while (tx >= cnt) { tx -= cnt; ++i_l; ++cnt; }
  const int j = tx;                       // key tile
  const int ig = 4 * panel + i_l;         // global q row-tile
  const int h = blockIdx.y;
  const int Kp = 512 * (panel + 1);
  const int r0g = ig * 128;

  const unsigned short* A = qbuf + (size_t)r0g * QLD + h * QK_DIM;
  const unsigned short* Bt = lat + (size_t)(j * 128) * LAT_LD;
  unsigned short* Eh = Ebuf + (size_t)h * 512 * Kp;

  GEMM_PROLOGUE();
  GEMM_KLOOP(A, QLD, Bt, LAT_LD, 0, 0, QK_DIM);

  // epilogue: scale -> mask -> exp -> store bf16 E, rowsum atomics
#pragma unroll
  for (int mi = 0; mi < 4; ++mi) {
    float rs[4] = {0.f, 0.f, 0.f, 0.f};
#pragma unroll
    for (int ni = 0; ni < 4; ++ni)
#pragma unroll
      for (int r = 0; r < 4; ++r) {
        int qr = r0g + wm * 64 + mi * 16 + quad * 4 + r;
        int key = j * 128 + wn * 64 + ni * 16 + l16;
        float e = (key <= qr) ? __expf(acc[mi][ni][r] * SCALE) : 0.f;
        rs[r] += e;
        Eh[(size_t)(qr - 512 * panel) * Kp + key] = f2bf(e);
      }
#pragma unroll
    for (int r = 0; r < 4; ++r) {
      float s = rs[r];
#pragma unroll
      for (int off = 1; off < 16; off <<= 1) s += __shfl_xor(s, off, 64);
      if (l16 == 0) {
        int qr = r0g + wm * 64 + mi * 16 + quad * 4 + r;
        atomicAdd(&lsum[h * TSEQ + qr], s);
      }
    }
  }
}

// ---------------- PV pass: y = (E @ V) / rowsum ----------------
// grid: (4 n-tiles, 4 m-tiles, 16 heads) per panel.
__global__ __launch_bounds__(256, 2) void pv_kernel(
    const unsigned short* __restrict__ Ebuf,
    const unsigned short* __restrict__ vtg,
    const float* __restrict__ lsum,
    unsigned short* __restrict__ ybuf, int panel) {
  const int i_l = blockIdx.y, h = blockIdx.z;
  const int n0 = blockIdx.x * 128;
  const int Kp = 512 * (panel + 1);
  const int ig = 4 * panel + i_l;
  const int Kmax = 128 * (ig + 1);        // causal extent for this row tile

  const unsigned short* A = Ebuf + (size_t)h * 512 * Kp + (size_t)(i_l * 128) * Kp;
  const unsigned short* Bt = vtg;

  GEMM_PROLOGUE();
  GEMM_KLOOP(A, Kp, Bt, TSEQ, 0, n0, Kmax);

#pragma unroll
  for (int mi = 0; mi < 4; ++mi)
#pragma unroll
    for (int r = 0; r < 4; ++r) {
      int row_g = 512 * panel + i_l * 128 + wm * 64 + mi * 16 + quad * 4 + r;
      float inv = 1.f / lsum[h * TSEQ + row_g];
#pragma unroll
      for (int ni = 0; ni < 4; ++ni) {
        int col = h * V_DIM + n0 + wn * 64 + ni * 16 + l16;
        ybuf[(size_t)row_g * YLD + col] = f2bf(acc[mi][ni][r] * inv);
      }
    }
}

// ---------------- RoPE ----------------
__global__ __launch_bounds__(256) void rope_k(unsigned short* __restrict__ lat,
                                              const float* __restrict__ cosb,
                                              const float* __restrict__ sinb) {
  int idx = blockIdx.x * 256 + threadIdx.x;
  if (idx >= TSEQ * 32) return;
  int t = idx >> 5, d = idx & 31;
  unsigned short* p = &lat[(size_t)t * LAT_LD + 512];
  union { unsigned int u; float f; } a, b;
  a.u = ((unsigned int)p[d]) << 16; b.u = ((unsigned int)p[d + 32]) << 16;
  float c0 = cosb[t * 64 + d], s0 = sinb[t * 64 + d];
  float c1 = cosb[t * 64 + d + 32], s1 = sinb[t * 64 + d + 32];
  p[d] = f2bf(a.f * c0 - b.f * s0);
  p[d + 32] = f2bf(b.f * c1 + a.f * s1);
}

__global__ __launch_bounds__(256) void rope_q(unsigned short* __restrict__ q,
                                              const float* __restrict__ cosb,
                                              const float* __restrict__ sinb) {
  int idx = blockIdx.x * 256 + threadIdx.x;
  if (idx >= TSEQ * NHEAD * 32) return;
  int t = idx >> 9, h = (idx >> 5) & 15, d = idx & 31;
  unsigned short* p = &q[(size_t)t * QLD + h * QK_DIM + 512];
  union { unsigned int u; float f; } a, b;
  a.u = ((unsigned int)p[d]) << 16; b.u = ((unsigned int)p[d + 32]) << 16;
  float c0 = cosb[t * 64 + d], s0 = sinb[t * 64 + d];
  float c1 = cosb[t * 64 + d + 32], s1 = sinb[t * 64 + d + 32];
  p[d] = f2bf(a.f * c0 - b.f * s0);
  p[d + 32] = f2bf(b.f * c1 + a.f * s1);
}

// ---------------- launch ----------------
extern "C" void kernel_launch(void* const* d_in, const int* in_sizes, int n_in,
                              void* d_out, int out_size, void* d_ws, size_t ws_size,
                              hipStream_t stream) {
  (void)in_sizes; (void)n_in; (void)out_size; (void)ws_size;
  const float* x     = (const float*)d_in[0];
  const float* cosb  = (const float*)d_in[1];
  const float* sinb  = (const float*)d_in[2];
  const float* wqkv  = (const float*)d_in[3];
  const float* wqdec = (const float*)d_in[4];
  const float* wout  = (const float*)d_in[5];
  float* out = (float*)d_out;

  unsigned short* ws     = (unsigned short*)d_ws;
  unsigned short* xb     = ws;                                  // 2048*2048
  unsigned short* wqkvT  = xb     + (size_t)2048 * 2048;        // 1664*2048 (rows 1600+ zero)
  unsigned short* wqdecT = wqkvT  + (size_t)1664 * 2048;        // 9216*1024
  unsigned short* woutT  = wqdecT + (size_t)9216 * 1024;        // 2048*8192
  unsigned short* lat    = woutT  + (size_t)2048 * 8192;        // 2048*1664
  unsigned short* qbuf   = lat    + (size_t)2048 * 1664;        // 2048*9216
  unsigned short* ybuf   = qbuf   + (size_t)2048 * 9216;        // 2048*8192
  unsigned short* vtg    = ybuf   + (size_t)2048 * 8192;        // 512*2048
  float*          lsumf  = (float*)(vtg + (size_t)512 * 2048);  // 16*2048 fp32
  // E panels alias xb..wqdecT (16.78M shorts needed, 17.04M available, dead after gemm2)
  unsigned short* Ebuf   = ws;

  conv_flat<<<4096, 256, 0, stream>>>(x, xb, 2048 * 2048);
  conv_t<<<dim3(32, 26), 256, 0, stream>>>(wqkv, 2048, 1600, wqkvT);
  conv_t<<<dim3(16, 144), 256, 0, stream>>>(wqdec, 1024, 9216, wqdecT);
  conv_t<<<dim3(128, 32), 256, 0, stream>>>(wout, 8192, 2048, woutT);
  hipMemsetAsync(lsumf, 0, NHEAD * TSEQ * sizeof(float), stream);

  // latents = x @ W_qkv   -> bf16 [2048][1664]
  gemm_bt<0><<<dim3(13, 16), 256, 0, stream>>>(xb, 2048, wqkvT, 2048, lat, LAT_LD, 2048);
  rope_k<<<256, 256, 0, stream>>>(lat, cosb, sinb);
  vtrans<<<dim3(32, 8), 256, 0, stream>>>(lat, vtg);

  // q = c_q @ W_qdec      -> bf16 [2048][9216]
  gemm_bt<0><<<dim3(72, 16), 256, 0, stream>>>(lat + 576, LAT_LD, wqdecT, 1024, qbuf, QLD, 1024);
  rope_q<<<4096, 256, 0, stream>>>(qbuf, cosb, sinb);

  // attention: 4 panels of 512 q-rows; E materialized per panel, then PV
  for (int p = 0; p < 4; ++p) {
    qke_kernel<<<dim3(16 * p + 10, 16), 256, 0, stream>>>(qbuf, lat, Ebuf, lsumf, p);
    pv_kernel<<<dim3(4, 4, 16), 256, 0, stream>>>(Ebuf, vtg, lsumf, ybuf, p);
  }

  // out = y @ W_out       -> fp32 d_out
  gemm_bt<1><<<dim3(16, 16), 256, 0, stream>>>(ybuf, YLD, woutT, 8192, out, 2048, 8192);
}

// Round 4
// 586.454 us; speedup vs baseline: 2.7433x; 1.1232x over previous
//
#include <hip/hip_runtime.h>

typedef __bf16 bf16x8_t __attribute__((ext_vector_type(8)));
typedef float f32x4_t __attribute__((ext_vector_type(4)));

#define LAT_LD 1664
#define QK_DIM 576
#define V_DIM 512
#define NHEAD 16
#define TSEQ 2048
#define QLD 9216
#define YLD 8192
#define SCALE 0.044194173824159216f

__device__ __forceinline__ unsigned short f2bf(float f) {
  union { float f; unsigned int u; } v; v.f = f;
  unsigned int r = v.u + 0x7FFFu + ((v.u >> 16) & 1u);
  return (unsigned short)(r >> 16);
}

// async global->LDS 16B (m97 pattern). LDS dest must be wave-uniform base + lane*16.
__device__ __forceinline__ void load_lds16(const unsigned short* g, unsigned short* l) {
  __builtin_amdgcn_global_load_lds((const __attribute__((address_space(1))) void*)g,
                                   (__attribute__((address_space(3))) void*)l, 16, 0, 0);
}

// ---------------- fp32 -> bf16 flat conversion (x) ----------------
__global__ __launch_bounds__(256) void conv_flat(const float* __restrict__ src,
                                                 unsigned short* __restrict__ dst, int n) {
  int i = (blockIdx.x * 256 + threadIdx.x) * 4;
  if (i < n) {
    float4 v = *(const float4*)&src[i];
    ushort4 o;
    o.x = f2bf(v.x); o.y = f2bf(v.y); o.z = f2bf(v.z); o.w = f2bf(v.w);
    *(ushort4*)&dst[i] = o;
  }
}

// ---------------- fp32 -> bf16 transpose-convert (weights) ----------------
__global__ __launch_bounds__(256) void conv_t(const float* __restrict__ src, int R, int Csrc,
                                              unsigned short* __restrict__ dst) {
  __shared__ unsigned short T[64][72];
  const int tid = threadIdx.x;
  const int r0 = blockIdx.x * 64, c0 = blockIdx.y * 64;
  const bool live = (c0 < Csrc);
#pragma unroll
  for (int it = 0; it < 4; ++it) {
    int idx = it * 256 + tid;
    int c4 = (idx >> 6) * 4;
    int r = idx & 63;
    float4 v = {0.f, 0.f, 0.f, 0.f};
    if (live) v = *(const float4*)&src[(size_t)(r0 + r) * Csrc + c0 + c4];
    T[c4 + 0][r] = f2bf(v.x);
    T[c4 + 1][r] = f2bf(v.y);
    T[c4 + 2][r] = f2bf(v.z);
    T[c4 + 3][r] = f2bf(v.w);
  }
  __syncthreads();
#pragma unroll
  for (int it = 0; it < 2; ++it) {
    int idx = it * 256 + tid;
    int cc = idx >> 3, r8 = (idx & 7) * 8;
    uint4 v = *(const uint4*)&T[cc][r8];
    *(uint4*)&dst[(size_t)(c0 + cc) * R + r0 + r8] = v;
  }
}

// ---------------- bf16 transpose: lat[:, 0:512] -> vtg[512][2048] ----------------
__global__ __launch_bounds__(256) void vtrans(const unsigned short* __restrict__ lat,
                                              unsigned short* __restrict__ vtg) {
  __shared__ unsigned short T[64][72];
  const int tid = threadIdx.x;
  const int r0 = blockIdx.x * 64, c0 = blockIdx.y * 64;
#pragma unroll
  for (int it = 0; it < 2; ++it) {
    int idx = it * 256 + tid;
    int c8 = (idx >> 6) * 8;
    int r = idx & 63;
    uint4 v = *(const uint4*)&lat[(size_t)(r0 + r) * LAT_LD + c0 + c8];
    unsigned short* pv = (unsigned short*)&v;
#pragma unroll
    for (int j = 0; j < 8; ++j) T[c8 + j][r] = pv[j];
  }
  __syncthreads();
#pragma unroll
  for (int it = 0; it < 2; ++it) {
    int idx = it * 256 + tid;
    int cc = idx >> 3, r8 = (idx & 7) * 8;
    uint4 v = *(const uint4*)&T[cc][r8];
    *(uint4*)&vtg[(size_t)(c0 + cc) * TSEQ + r0 + r8] = v;
  }
}

// ---------------- m97-style GEMM core ----------------
#define GEMM_PROLOGUE()                                                     \
  __shared__ __align__(16) unsigned short As[4096];                         \
  __shared__ __align__(16) unsigned short Bs[4096];                         \
  const int tid = threadIdx.x;                                              \
  const int wave = tid >> 6, lane = tid & 63;                               \
  const int quad = lane >> 4, l16 = lane & 15;                              \
  const int wm = wave >> 1, wn = wave & 1;                                  \
  f32x4_t acc[4][4];                                                        \
  f32x4_t zero = {0.f, 0.f, 0.f, 0.f};                                      \
  _Pragma("unroll") for (int mi = 0; mi < 4; ++mi)                          \
    _Pragma("unroll") for (int ni = 0; ni < 4; ++ni) acc[mi][ni] = zero;

#define GEMM_KLOOP(Aptr, Alda, Bptr, Bldb, M0, N0, KLEN)                    \
  for (int k0 = 0; k0 < (KLEN); k0 += 32) {                                 \
    _Pragma("unroll") for (int p2 = 0; p2 < 2; ++p2) {                      \
      int ci = p2 * 256 + tid;                                              \
      int rr2 = ci >> 2, cc2 = (ci & 3) * 8;                                \
      load_lds16(&(Aptr)[(size_t)((M0) + rr2) * (Alda) + k0 + cc2], &As[ci * 8]); \
      load_lds16(&(Bptr)[(size_t)((N0) + rr2) * (Bldb) + k0 + cc2], &Bs[ci * 8]); \
    }                                                                       \
    __syncthreads();                                                        \
    bf16x8_t af[4], bfr[4];                                                 \
    _Pragma("unroll") for (int mi = 0; mi < 4; ++mi)                        \
      af[mi] = *(const bf16x8_t*)&As[(wm * 64 + mi * 16 + l16) * 32 + quad * 8]; \
    _Pragma("unroll") for (int ni = 0; ni < 4; ++ni)                        \
      bfr[ni] = *(const bf16x8_t*)&Bs[(wn * 64 + ni * 16 + l16) * 32 + quad * 8]; \
    _Pragma("unroll") for (int mi = 0; mi < 4; ++mi)                        \
      _Pragma("unroll") for (int ni = 0; ni < 4; ++ni)                      \
        acc[mi][ni] = __builtin_amdgcn_mfma_f32_16x16x32_bf16(af[mi], bfr[ni], acc[mi][ni], 0, 0, 0); \
    __syncthreads();                                                        \
  }

// ---------------- plain GEMM: C[M,N] = A[M,K] @ Bt[N,K]^T ----------------
template <int OUTF32>
__global__ __launch_bounds__(256, 2) void gemm_bt(
    const unsigned short* __restrict__ A, int lda,
    const unsigned short* __restrict__ Bt, int ldb,
    void* __restrict__ C, int ldc, int K) {
  const int m0 = blockIdx.y * 128, n0 = blockIdx.x * 128;
  GEMM_PROLOGUE();
  GEMM_KLOOP(A, lda, Bt, ldb, m0, n0, K);
#pragma unroll
  for (int mi = 0; mi < 4; ++mi)
#pragma unroll
    for (int ni = 0; ni < 4; ++ni)
#pragma unroll
      for (int r = 0; r < 4; ++r) {
        int row = m0 + wm * 64 + mi * 16 + quad * 4 + r;
        int col = n0 + wn * 64 + ni * 16 + l16;
        if (OUTF32)
          ((float*)C)[(size_t)row * ldc + col] = acc[mi][ni][r];
        else
          ((unsigned short*)C)[(size_t)row * ldc + col] = f2bf(acc[mi][ni][r]);
      }
}

// ---------------- split-K GEMM: P[s][M][N] fp32 partials, slice K = Ks ----------------
__global__ __launch_bounds__(256, 2) void gemm_splitk(
    const unsigned short* __restrict__ A, int lda,
    const unsigned short* __restrict__ Bt, int ldb,
    float* __restrict__ P, int ldc, int Ks) {
  const int m0 = blockIdx.y * 128, n0 = blockIdx.x * 128;
  const size_t koff = (size_t)blockIdx.z * Ks;
  const unsigned short* Ap = A + koff;
  const unsigned short* Bp = Bt + koff;
  float* C = P + (size_t)blockIdx.z * ((size_t)gridDim.y * 128) * ldc;
  GEMM_PROLOGUE();
  GEMM_KLOOP(Ap, lda, Bp, ldb, m0, n0, Ks);
#pragma unroll
  for (int mi = 0; mi < 4; ++mi)
#pragma unroll
    for (int ni = 0; ni < 4; ++ni)
#pragma unroll
      for (int r = 0; r < 4; ++r) {
        int row = m0 + wm * 64 + mi * 16 + quad * 4 + r;
        int col = n0 + wn * 64 + ni * 16 + l16;
        C[(size_t)row * ldc + col] = acc[mi][ni][r];
      }
}

// ---------------- split-K reductions ----------------
__global__ __launch_bounds__(256) void reduce2_bf(const float* __restrict__ p,
                                                  unsigned short* __restrict__ dst, int n) {
  int i = (blockIdx.x * 256 + threadIdx.x) * 4;
  if (i < n) {
    float4 a = *(const float4*)&p[i];
    float4 b = *(const float4*)&p[(size_t)n + i];
    ushort4 o;
    o.x = f2bf(a.x + b.x); o.y = f2bf(a.y + b.y);
    o.z = f2bf(a.z + b.z); o.w = f2bf(a.w + b.w);
    *(ushort4*)&dst[i] = o;
  }
}

__global__ __launch_bounds__(256) void reduce4_f32(const float* __restrict__ p,
                                                   float* __restrict__ dst, int n) {
  int i = (blockIdx.x * 256 + threadIdx.x) * 4;
  if (i < n) {
    float4 a = *(const float4*)&p[i];
    float4 b = *(const float4*)&p[(size_t)n + i];
    float4 c = *(const float4*)&p[2 * (size_t)n + i];
    float4 d = *(const float4*)&p[3 * (size_t)n + i];
    float4 o;
    o.x = (a.x + b.x) + (c.x + d.x);
    o.y = (a.y + b.y) + (c.y + d.y);
    o.z = (a.z + b.z) + (c.z + d.z);
    o.w = (a.w + b.w) + (c.w + d.w);
    *(float4*)&dst[i] = o;
  }
}

// ---------------- QK^T + exp pass, panel of q-tiles [tq0, tq1) ----------------
// grid: (sum_{i=tq0..tq1-1}(i+1), 16 heads). E[h][Rp][Kp] bf16, Kp = tq1*128.
__global__ __launch_bounds__(256, 2) void qke_kernel(
    const unsigned short* __restrict__ qbuf,
    const unsigned short* __restrict__ lat,
    unsigned short* __restrict__ Ebuf,
    float* __restrict__ lsum, int tq0, int tq1) {
  int tx = blockIdx.x, i_l = 0, cnt = tq0 + 1;
  while (tx >= cnt) { tx -= cnt; ++i_l; ++cnt; }
  const int j = tx;                       // key tile
  const int ig = tq0 + i_l;               // global q row-tile
  const int h = blockIdx.y;
  const int Kp = tq1 << 7;
  const int Rp = (tq1 - tq0) << 7;
  const int r0g = ig << 7;

  const unsigned short* A = qbuf + (size_t)r0g * QLD + h * QK_DIM;
  const unsigned short* Bt = lat + (size_t)(j << 7) * LAT_LD;
  unsigned short* Eh = Ebuf + (size_t)h * Rp * Kp;

  GEMM_PROLOGUE();
  GEMM_KLOOP(A, QLD, Bt, LAT_LD, 0, 0, QK_DIM);

#pragma unroll
  for (int mi = 0; mi < 4; ++mi) {
    float rs[4] = {0.f, 0.f, 0.f, 0.f};
#pragma unroll
    for (int ni = 0; ni < 4; ++ni)
#pragma unroll
      for (int r = 0; r < 4; ++r) {
        int qr = r0g + wm * 64 + mi * 16 + quad * 4 + r;
        int key = (j << 7) + wn * 64 + ni * 16 + l16;
        float e = (key <= qr) ? __expf(acc[mi][ni][r] * SCALE) : 0.f;
        rs[r] += e;
        Eh[(size_t)(qr - (tq0 << 7)) * Kp + key] = f2bf(e);
      }
#pragma unroll
    for (int r = 0; r < 4; ++r) {
      float s = rs[r];
#pragma unroll
      for (int off = 1; off < 16; off <<= 1) s += __shfl_xor(s, off, 64);
      if (l16 == 0) {
        int qr = r0g + wm * 64 + mi * 16 + quad * 4 + r;
        atomicAdd(&lsum[h * TSEQ + qr], s);
      }
    }
  }
}

// ---------------- PV pass: y = (E @ V) / rowsum ----------------
// grid: (4 n-tiles, tq1-tq0 m-tiles, 16 heads)
__global__ __launch_bounds__(256, 2) void pv_kernel(
    const unsigned short* __restrict__ Ebuf,
    const unsigned short* __restrict__ vtg,
    const float* __restrict__ lsum,
    unsigned short* __restrict__ ybuf, int tq0, int tq1) {
  const int i_l = blockIdx.y, h = blockIdx.z;
  const int n0 = blockIdx.x * 128;
  const int Kp = tq1 << 7;
  const int Rp = (tq1 - tq0) << 7;
  const int Kmax = (tq0 + i_l + 1) << 7;  // causal extent

  const unsigned short* A = Ebuf + (size_t)h * Rp * Kp + (size_t)(i_l << 7) * Kp;
  const unsigned short* Bt = vtg;

  GEMM_PROLOGUE();
  GEMM_KLOOP(A, Kp, Bt, TSEQ, 0, n0, Kmax);

#pragma unroll
  for (int mi = 0; mi < 4; ++mi)
#pragma unroll
    for (int r = 0; r < 4; ++r) {
      int row_g = ((tq0 + i_l) << 7) + wm * 64 + mi * 16 + quad * 4 + r;
      float inv = 1.f / lsum[h * TSEQ + row_g];
#pragma unroll
      for (int ni = 0; ni < 4; ++ni) {
        int col = h * V_DIM + n0 + wn * 64 + ni * 16 + l16;
        ybuf[(size_t)row_g * YLD + col] = f2bf(acc[mi][ni][r] * inv);
      }
    }
}

// ---------------- RoPE ----------------
__global__ __launch_bounds__(256) void rope_k(unsigned short* __restrict__ lat,
                                              const float* __restrict__ cosb,
                                              const float* __restrict__ sinb) {
  int idx = blockIdx.x * 256 + threadIdx.x;
  if (idx >= TSEQ * 32) return;
  int t = idx >> 5, d = idx & 31;
  unsigned short* p = &lat[(size_t)t * LAT_LD + 512];
  union { unsigned int u; float f; } a, b;
  a.u = ((unsigned int)p[d]) << 16; b.u = ((unsigned int)p[d + 32]) << 16;
  float c0 = cosb[t * 64 + d], s0 = sinb[t * 64 + d];
  float c1 = cosb[t * 64 + d + 32], s1 = sinb[t * 64 + d + 32];
  p[d] = f2bf(a.f * c0 - b.f * s0);
  p[d + 32] = f2bf(b.f * c1 + a.f * s1);
}

__global__ __launch_bounds__(256) void rope_q(unsigned short* __restrict__ q,
                                              const float* __restrict__ cosb,
                                              const float* __restrict__ sinb) {
  int idx = blockIdx.x * 256 + threadIdx.x;
  if (idx >= TSEQ * NHEAD * 32) return;
  int t = idx >> 9, h = (idx >> 5) & 15, d = idx & 31;
  unsigned short* p = &q[(size_t)t * QLD + h * QK_DIM + 512];
  union { unsigned int u; float f; } a, b;
  a.u = ((unsigned int)p[d]) << 16; b.u = ((unsigned int)p[d + 32]) << 16;
  float c0 = cosb[t * 64 + d], s0 = sinb[t * 64 + d];
  float c1 = cosb[t * 64 + d + 32], s1 = sinb[t * 64 + d + 32];
  p[d] = f2bf(a.f * c0 - b.f * s0);
  p[d + 32] = f2bf(b.f * c1 + a.f * s1);
}

// ---------------- launch ----------------
extern "C" void kernel_launch(void* const* d_in, const int* in_sizes, int n_in,
                              void* d_out, int out_size, void* d_ws, size_t ws_size,
                              hipStream_t stream) {
  (void)in_sizes; (void)n_in; (void)out_size; (void)ws_size;
  const float* x     = (const float*)d_in[0];
  const float* cosb  = (const float*)d_in[1];
  const float* sinb  = (const float*)d_in[2];
  const float* wqkv  = (const float*)d_in[3];
  const float* wqdec = (const float*)d_in[4];
  const float* wout  = (const float*)d_in[5];
  float* out = (float*)d_out;

  // ws layout (shorts). Dead-at-end region xb..qbuf is contiguous for split-K partials.
  unsigned short* ws     = (unsigned short*)d_ws;
  unsigned short* xb     = ws;                                  // 4,194,304
  unsigned short* wqkvT  = xb     + (size_t)2048 * 2048;        // 3,407,872 (rows 1600+ zero)
  unsigned short* wqdecT = wqkvT  + (size_t)1664 * 2048;        // 9,437,184
  unsigned short* lat    = wqdecT + (size_t)9216 * 1024;        // 3,407,872
  unsigned short* qbuf   = lat    + (size_t)2048 * 1664;        // 18,874,368
  unsigned short* woutT  = qbuf   + (size_t)2048 * 9216;        // 16,777,216
  unsigned short* ybuf   = woutT  + (size_t)2048 * 8192;        // 16,777,216
  unsigned short* vtg    = ybuf   + (size_t)2048 * 8192;        // 1,048,576
  float*          lsumf  = (float*)(vtg + (size_t)512 * 2048);  // 32,768 floats
  // E panels alias xb..wqdecT (need <= 16.78M shorts, have 17.04M)
  unsigned short* Ebuf   = ws;
  // gemm1 split-K partials alias qbuf (need 13.6M shorts, have 18.9M)
  float*          P1     = (float*)qbuf;
  // final split-K partials alias xb..lat+qbuf-part (need 33.55M shorts, woutT at 39.3M)
  float*          Pf     = (float*)ws;

  conv_flat<<<4096, 256, 0, stream>>>(x, xb, 2048 * 2048);
  conv_t<<<dim3(32, 26), 256, 0, stream>>>(wqkv, 2048, 1600, wqkvT);
  conv_t<<<dim3(16, 144), 256, 0, stream>>>(wqdec, 1024, 9216, wqdecT);
  conv_t<<<dim3(128, 32), 256, 0, stream>>>(wout, 8192, 2048, woutT);
  hipMemsetAsync(lsumf, 0, NHEAD * TSEQ * sizeof(float), stream);

  // latents = x @ W_qkv  (split-K x2 -> fp32 partials -> bf16 lat)
  gemm_splitk<<<dim3(13, 16, 2), 256, 0, stream>>>(xb, 2048, wqkvT, 2048, P1, 1664, 1024);
  reduce2_bf<<<3328, 256, 0, stream>>>(P1, lat, 2048 * 1664);
  rope_k<<<256, 256, 0, stream>>>(lat, cosb, sinb);
  vtrans<<<dim3(32, 8), 256, 0, stream>>>(lat, vtg);

  // q = c_q @ W_qdec  (1152 blocks, already >=4/CU)
  gemm_bt<0><<<dim3(72, 16), 256, 0, stream>>>(lat + 576, LAT_LD, wqdecT, 1024, qbuf, QLD, 1024);
  rope_q<<<4096, 256, 0, stream>>>(qbuf, cosb, sinb);

  // attention: 3 panels of q-tiles [0,8), [8,12), [12,16)
  qke_kernel<<<dim3(36, 16), 256, 0, stream>>>(qbuf, lat, Ebuf, lsumf, 0, 8);
  pv_kernel<<<dim3(4, 8, 16), 256, 0, stream>>>(Ebuf, vtg, lsumf, ybuf, 0, 8);
  qke_kernel<<<dim3(42, 16), 256, 0, stream>>>(qbuf, lat, Ebuf, lsumf, 8, 12);
  pv_kernel<<<dim3(4, 4, 16), 256, 0, stream>>>(Ebuf, vtg, lsumf, ybuf, 8, 12);
  qke_kernel<<<dim3(58, 16), 256, 0, stream>>>(qbuf, lat, Ebuf, lsumf, 12, 16);
  pv_kernel<<<dim3(4, 4, 16), 256, 0, stream>>>(Ebuf, vtg, lsumf, ybuf, 12, 16);

  // out = y @ W_out  (split-K x4 -> fp32 partials -> fp32 out)
  gemm_splitk<<<dim3(16, 16, 4), 256, 0, stream>>>(ybuf, YLD, woutT, 8192, Pf, 2048, 2048);
  reduce4_f32<<<4096, 256, 0, stream>>>(Pf, out, 2048 * 2048);
}

// Round 5
// 544.761 us; speedup vs baseline: 2.9533x; 1.0765x over previous
//
#include <hip/hip_runtime.h>

typedef __bf16 bf16x8_t __attribute__((ext_vector_type(8)));
typedef float f32x4_t __attribute__((ext_vector_type(4)));

#define LAT_LD 1664
#define QK_DIM 576
#define V_DIM 512
#define NHEAD 16
#define TSEQ 2048
#define QLD 9216
#define YLD 8192
#define KLD 576
#define SCALE 0.044194173824159216f

__device__ __forceinline__ unsigned short f2bf(float f) {
  union { float f; unsigned int u; } v; v.f = f;
  unsigned int r = v.u + 0x7FFFu + ((v.u >> 16) & 1u);
  return (unsigned short)(r >> 16);
}

// async global->LDS 16B (m97 pattern). LDS dest must be wave-uniform base + lane*16.
__device__ __forceinline__ void load_lds16(const unsigned short* g, unsigned short* l) {
  __builtin_amdgcn_global_load_lds((const __attribute__((address_space(1))) void*)g,
                                   (__attribute__((address_space(3))) void*)l, 16, 0, 0);
}

// ---------------- fused prep: x->bf16, 3x transpose-convert, lsum zero ----------------
__device__ __forceinline__ void conv_t_body(const float* __restrict__ src, int R, int Csrc,
                                            unsigned short* __restrict__ dst,
                                            int bx, int by, int tid,
                                            unsigned short (*T)[72]) {
  const int r0 = bx * 64, c0 = by * 64;
  const bool live = (c0 < Csrc);
#pragma unroll
  for (int it = 0; it < 4; ++it) {
    int idx = it * 256 + tid;
    int c4 = (idx >> 6) * 4;
    int r = idx & 63;
    float4 v = {0.f, 0.f, 0.f, 0.f};
    if (live) v = *(const float4*)&src[(size_t)(r0 + r) * Csrc + c0 + c4];
    T[c4 + 0][r] = f2bf(v.x);
    T[c4 + 1][r] = f2bf(v.y);
    T[c4 + 2][r] = f2bf(v.z);
    T[c4 + 3][r] = f2bf(v.w);
  }
  __syncthreads();
#pragma unroll
  for (int it = 0; it < 2; ++it) {
    int idx = it * 256 + tid;
    int cc = idx >> 3, r8 = (idx & 7) * 8;
    uint4 v = *(const uint4*)&T[cc][r8];
    *(uint4*)&dst[(size_t)(c0 + cc) * R + r0 + r8] = v;
  }
}

// jobs: [0,4096) conv x; [4096,4928) wqkvT; [4928,7232) wqdecT; [7232,11328) woutT;
//       [11328,11360) zero lsum
__global__ __launch_bounds__(256) void prep_all(
    const float* __restrict__ x, unsigned short* __restrict__ xb,
    const float* __restrict__ wqkv, unsigned short* __restrict__ wqkvT,
    const float* __restrict__ wqdec, unsigned short* __restrict__ wqdecT,
    const float* __restrict__ wout, unsigned short* __restrict__ woutT,
    float* __restrict__ lsum) {
  __shared__ unsigned short T[64][72];
  const int blk = blockIdx.x, tid = threadIdx.x;
  if (blk < 4096) {
    int i = (blk * 256 + tid) * 4;
    float4 v = *(const float4*)&x[i];
    ushort4 o;
    o.x = f2bf(v.x); o.y = f2bf(v.y); o.z = f2bf(v.z); o.w = f2bf(v.w);
    *(ushort4*)&xb[i] = o;
  } else if (blk < 4928) {
    int l = blk - 4096;
    conv_t_body(wqkv, 2048, 1600, wqkvT, l & 31, l >> 5, tid, T);
  } else if (blk < 7232) {
    int l = blk - 4928;
    conv_t_body(wqdec, 1024, 9216, wqdecT, l & 15, l >> 4, tid, T);
  } else if (blk < 11328) {
    int l = blk - 7232;
    conv_t_body(wout, 8192, 2048, woutT, l & 127, l >> 7, tid, T);
  } else {
    int i = ((blk - 11328) * 256 + tid) * 4;
    *(float4*)&lsum[i] = (float4){0.f, 0.f, 0.f, 0.f};
  }
}

// ---------------- vtrans + compact-K copy: lat[:,0:512] -> vtg[512][2048] and kbuf ----------------
__global__ __launch_bounds__(256) void vtrans_kcopy(const unsigned short* __restrict__ lat,
                                                    unsigned short* __restrict__ vtg,
                                                    unsigned short* __restrict__ kbuf) {
  __shared__ unsigned short T[64][72];
  const int tid = threadIdx.x;
  const int r0 = blockIdx.x * 64, c0 = blockIdx.y * 64;
#pragma unroll
  for (int it = 0; it < 2; ++it) {
    int idx = it * 256 + tid;
    int c8 = (idx >> 6) * 8;
    int r = idx & 63;
    uint4 v = *(const uint4*)&lat[(size_t)(r0 + r) * LAT_LD + c0 + c8];
    *(uint4*)&kbuf[(size_t)(r0 + r) * KLD + c0 + c8] = v;
    unsigned short* pv = (unsigned short*)&v;
#pragma unroll
    for (int j = 0; j < 8; ++j) T[c8 + j][r] = pv[j];
  }
  __syncthreads();
#pragma unroll
  for (int it = 0; it < 2; ++it) {
    int idx = it * 256 + tid;
    int cc = idx >> 3, r8 = (idx & 7) * 8;
    uint4 v = *(const uint4*)&T[cc][r8];
    *(uint4*)&vtg[(size_t)(c0 + cc) * TSEQ + r0 + r8] = v;
  }
}

// ---------------- RoPE on K: lat cols 512..575 -> kbuf cols 512..575 ----------------
__global__ __launch_bounds__(256) void rope_k(const unsigned short* __restrict__ lat,
                                              unsigned short* __restrict__ kbuf,
                                              const float* __restrict__ cosb,
                                              const float* __restrict__ sinb) {
  int idx = blockIdx.x * 256 + threadIdx.x;
  if (idx >= TSEQ * 32) return;
  int t = idx >> 5, d = idx & 31;
  const unsigned short* p = &lat[(size_t)t * LAT_LD + 512];
  union { unsigned int u; float f; } a, b;
  a.u = ((unsigned int)p[d]) << 16; b.u = ((unsigned int)p[d + 32]) << 16;
  float c0 = cosb[t * 64 + d], s0 = sinb[t * 64 + d];
  float c1 = cosb[t * 64 + d + 32], s1 = sinb[t * 64 + d + 32];
  kbuf[(size_t)t * KLD + 512 + d] = f2bf(a.f * c0 - b.f * s0);
  kbuf[(size_t)t * KLD + 544 + d] = f2bf(b.f * c1 + a.f * s1);
}

// ---------------- m97-style GEMM core ----------------
#define GEMM_PROLOGUE()                                                     \
  __shared__ __align__(16) unsigned short As[4096];                         \
  __shared__ __align__(16) unsigned short Bs[4096];                         \
  const int tid = threadIdx.x;                                              \
  const int wave = tid >> 6, lane = tid & 63;                               \
  const int quad = lane >> 4, l16 = lane & 15;                              \
  const int wm = wave >> 1, wn = wave & 1;                                  \
  f32x4_t acc[4][4];                                                        \
  f32x4_t zero = {0.f, 0.f, 0.f, 0.f};                                      \
  _Pragma("unroll") for (int mi = 0; mi < 4; ++mi)                          \
    _Pragma("unroll") for (int ni = 0; ni < 4; ++ni) acc[mi][ni] = zero;

#define GEMM_KLOOP(Aptr, Alda, Bptr, Bldb, M0, N0, KLEN)                    \
  for (int k0 = 0; k0 < (KLEN); k0 += 32) {                                 \
    _Pragma("unroll") for (int p2 = 0; p2 < 2; ++p2) {                      \
      int ci = p2 * 256 + tid;                                              \
      int rr2 = ci >> 2, cc2 = (ci & 3) * 8;                                \
      load_lds16(&(Aptr)[(size_t)((M0) + rr2) * (Alda) + k0 + cc2], &As[ci * 8]); \
      load_lds16(&(Bptr)[(size_t)((N0) + rr2) * (Bldb) + k0 + cc2], &Bs[ci * 8]); \
    }                                                                       \
    __syncthreads();                                                        \
    bf16x8_t af[4], bfr[4];                                                 \
    _Pragma("unroll") for (int mi = 0; mi < 4; ++mi)                        \
      af[mi] = *(const bf16x8_t*)&As[(wm * 64 + mi * 16 + l16) * 32 + quad * 8]; \
    _Pragma("unroll") for (int ni = 0; ni < 4; ++ni)                        \
      bfr[ni] = *(const bf16x8_t*)&Bs[(wn * 64 + ni * 16 + l16) * 32 + quad * 8]; \
    _Pragma("unroll") for (int mi = 0; mi < 4; ++mi)                        \
      _Pragma("unroll") for (int ni = 0; ni < 4; ++ni)                      \
        acc[mi][ni] = __builtin_amdgcn_mfma_f32_16x16x32_bf16(af[mi], bfr[ni], acc[mi][ni], 0, 0, 0); \
    __syncthreads();                                                        \
  }

// ---------------- split-K GEMM: P[s][M][N] fp32 partials, slice K = Ks ----------------
__global__ __launch_bounds__(256, 2) void gemm_splitk(
    const unsigned short* __restrict__ A, int lda,
    const unsigned short* __restrict__ Bt, int ldb,
    float* __restrict__ P, int ldc, int Ks) {
  const int m0 = blockIdx.y * 128, n0 = blockIdx.x * 128;
  const size_t koff = (size_t)blockIdx.z * Ks;
  const unsigned short* Ap = A + koff;
  const unsigned short* Bp = Bt + koff;
  float* C = P + (size_t)blockIdx.z * ((size_t)gridDim.y * 128) * ldc;
  GEMM_PROLOGUE();
  GEMM_KLOOP(Ap, lda, Bp, ldb, m0, n0, Ks);
#pragma unroll
  for (int mi = 0; mi < 4; ++mi)
#pragma unroll
    for (int ni = 0; ni < 4; ++ni)
#pragma unroll
      for (int r = 0; r < 4; ++r) {
        int row = m0 + wm * 64 + mi * 16 + quad * 4 + r;
        int col = n0 + wn * 64 + ni * 16 + l16;
        C[(size_t)row * ldc + col] = acc[mi][ni][r];
      }
}

// ---------------- gemm2 with fused RoPE-q epilogue: qbuf = rope(c_q @ W_qdec) ----------------
__global__ __launch_bounds__(256, 2) void gemm_qdec(
    const unsigned short* __restrict__ A,      // lat + 576 (c_q), lda LAT_LD
    const unsigned short* __restrict__ Bt,     // wqdecT [9216][1024]
    unsigned short* __restrict__ qbuf,
    const float* __restrict__ cosb, const float* __restrict__ sinb) {
  const int m0 = blockIdx.y * 128, n0 = blockIdx.x * 128;
  GEMM_PROLOGUE();
  GEMM_KLOOP(A, LAT_LD, Bt, 1024, m0, n0, 1024);

  const int cb = n0 + wn * 64;                 // this wave's 64-col half
  const bool ropeh = (cb % QK_DIM) == 512;     // rope region is 64-aligned, 64 wide
#pragma unroll
  for (int mi = 0; mi < 4; ++mi)
#pragma unroll
    for (int r = 0; r < 4; ++r) {
      int t = m0 + wm * 64 + mi * 16 + quad * 4 + r;
      if (ropeh) {
#pragma unroll
        for (int ni = 0; ni < 2; ++ni) {
          int d = ni * 16 + l16;
          float c0f = cosb[t * 64 + d], s0f = sinb[t * 64 + d];
          float c1f = cosb[t * 64 + d + 32], s1f = sinb[t * 64 + d + 32];
          float v1 = acc[mi][ni][r], v2 = acc[mi][ni + 2][r];
          qbuf[(size_t)t * QLD + cb + d] = f2bf(v1 * c0f - v2 * s0f);
          qbuf[(size_t)t * QLD + cb + 32 + d] = f2bf(v2 * c1f + v1 * s1f);
        }
      } else {
#pragma unroll
        for (int ni = 0; ni < 4; ++ni)
          qbuf[(size_t)t * QLD + cb + ni * 16 + l16] = f2bf(acc[mi][ni][r]);
      }
    }
}

// ---------------- split-K reductions ----------------
__global__ __launch_bounds__(256) void reduce2_bf(const float* __restrict__ p,
                                                  unsigned short* __restrict__ dst, int n) {
  int i = (blockIdx.x * 256 + threadIdx.x) * 4;
  if (i < n) {
    float4 a = *(const float4*)&p[i];
    float4 b = *(const float4*)&p[(size_t)n + i];
    ushort4 o;
    o.x = f2bf(a.x + b.x); o.y = f2bf(a.y + b.y);
    o.z = f2bf(a.z + b.z); o.w = f2bf(a.w + b.w);
    *(ushort4*)&dst[i] = o;
  }
}

__global__ __launch_bounds__(256) void reduce4_f32(const float* __restrict__ p,
                                                   float* __restrict__ dst, int n) {
  int i = (blockIdx.x * 256 + threadIdx.x) * 4;
  if (i < n) {
    float4 a = *(const float4*)&p[i];
    float4 b = *(const float4*)&p[(size_t)n + i];
    float4 c = *(const float4*)&p[2 * (size_t)n + i];
    float4 d = *(const float4*)&p[3 * (size_t)n + i];
    float4 o;
    o.x = (a.x + b.x) + (c.x + d.x);
    o.y = (a.y + b.y) + (c.y + d.y);
    o.z = (a.z + b.z) + (c.z + d.z);
    o.w = (a.w + b.w) + (c.w + d.w);
    *(float4*)&dst[i] = o;
  }
}

// ---------------- QK^T + exp pass, panel of q-tiles [tq0, tq1), packed-causal E ----------------
// E tile ig (128 rows) has Kmax=(ig+1)*128 cols, row-major ld=Kmax, packed per head.
// grid: (sum over panel of (ig+1), NHEAD), heavy row-tiles first.
__global__ __launch_bounds__(256, 2) void qke_kernel(
    const unsigned short* __restrict__ qbuf,
    const unsigned short* __restrict__ kbuf,
    unsigned short* __restrict__ Ebuf,
    float* __restrict__ lsum, int tq0, int tq1) {
  int tx = blockIdx.x, ig = tq1 - 1, cnt = tq1;
  while (tx >= cnt) { tx -= cnt; --ig; --cnt; }
  const int j = tx;                       // key tile
  const int h = blockIdx.y;
  const int Kmax = (ig + 1) << 7;
  const int r0g = ig << 7;
  const int panelSz = (tq1 * (tq1 + 1) - tq0 * (tq0 + 1)) >> 1;
  const int pre = (ig * (ig + 1) - tq0 * (tq0 + 1)) >> 1;

  const unsigned short* A = qbuf + (size_t)r0g * QLD + h * QK_DIM;
  const unsigned short* Bt = kbuf + (size_t)(j << 7) * KLD;
  unsigned short* Eh = Ebuf + ((size_t)h * panelSz + pre) * 16384;

  GEMM_PROLOGUE();
  GEMM_KLOOP(A, QLD, Bt, KLD, 0, 0, QK_DIM);

#pragma unroll
  for (int mi = 0; mi < 4; ++mi) {
    float rs[4] = {0.f, 0.f, 0.f, 0.f};
#pragma unroll
    for (int ni = 0; ni < 4; ++ni)
#pragma unroll
      for (int r = 0; r < 4; ++r) {
        int qr = r0g + wm * 64 + mi * 16 + quad * 4 + r;
        int key = (j << 7) + wn * 64 + ni * 16 + l16;
        float e = (key <= qr) ? __expf(acc[mi][ni][r] * SCALE) : 0.f;
        rs[r] += e;
        Eh[(size_t)(qr - r0g) * Kmax + key] = f2bf(e);
      }
#pragma unroll
    for (int r = 0; r < 4; ++r) {
      float s = rs[r];
#pragma unroll
      for (int off = 1; off < 16; off <<= 1) s += __shfl_xor(s, off, 64);
      if (l16 == 0) {
        int qr = r0g + wm * 64 + mi * 16 + quad * 4 + r;
        atomicAdd(&lsum[h * TSEQ + qr], s);
      }
    }
  }
}

// ---------------- PV pass: y = (E @ V) / rowsum ----------------
// grid: (4 n-tiles, tq1-tq0 m-tiles (reversed: heavy first), NHEAD)
__global__ __launch_bounds__(256, 2) void pv_kernel(
    const unsigned short* __restrict__ Ebuf,
    const unsigned short* __restrict__ vtg,
    const float* __restrict__ lsum,
    unsigned short* __restrict__ ybuf, int tq0, int tq1) {
  const int i_l = (tq1 - tq0 - 1) - blockIdx.y;   // heavy first
  const int ig = tq0 + i_l;
  const int h = blockIdx.z;
  const int n0 = blockIdx.x * 128;
  const int Kmax = (ig + 1) << 7;
  const int panelSz = (tq1 * (tq1 + 1) - tq0 * (tq0 + 1)) >> 1;
  const int pre = (ig * (ig + 1) - tq0 * (tq0 + 1)) >> 1;

  const unsigned short* A = Ebuf + ((size_t)h * panelSz + pre) * 16384;

  GEMM_PROLOGUE();
  GEMM_KLOOP(A, Kmax, vtg, TSEQ, 0, n0, Kmax);

#pragma unroll
  for (int mi = 0; mi < 4; ++mi)
#pragma unroll
    for (int r = 0; r < 4; ++r) {
      int row_g = (ig << 7) + wm * 64 + mi * 16 + quad * 4 + r;
      float inv = 1.f / lsum[h * TSEQ + row_g];
#pragma unroll
      for (int ni = 0; ni < 4; ++ni) {
        int col = h * V_DIM + n0 + wn * 64 + ni * 16 + l16;
        ybuf[(size_t)row_g * YLD + col] = f2bf(acc[mi][ni][r] * inv);
      }
    }
}

// ---------------- launch ----------------
extern "C" void kernel_launch(void* const* d_in, const int* in_sizes, int n_in,
                              void* d_out, int out_size, void* d_ws, size_t ws_size,
                              hipStream_t stream) {
  (void)in_sizes; (void)n_in; (void)out_size; (void)ws_size;
  const float* x     = (const float*)d_in[0];
  const float* cosb  = (const float*)d_in[1];
  const float* sinb  = (const float*)d_in[2];
  const float* wqkv  = (const float*)d_in[3];
  const float* wqdec = (const float*)d_in[4];
  const float* wout  = (const float*)d_in[5];
  float* out = (float*)d_out;

  // ws layout (shorts). [xb, wqkvT, wqdecT, lat] all dead by attention time -> Ebuf alias.
  unsigned short* ws     = (unsigned short*)d_ws;
  unsigned short* xb     = ws;                                  //  4,194,304
  unsigned short* wqkvT  = xb     + (size_t)2048 * 2048;        //  3,407,872
  unsigned short* wqdecT = wqkvT  + (size_t)1664 * 2048;        //  9,437,184
  unsigned short* lat    = wqdecT + (size_t)9216 * 1024;        //  3,407,872  (ends 20,447,232)
  unsigned short* qbuf   = lat    + (size_t)2048 * 1664;        // 18,874,368  (ends 39,321,600)
  unsigned short* woutT  = qbuf   + (size_t)2048 * 9216;        // 16,777,216
  unsigned short* ybuf   = woutT  + (size_t)2048 * 8192;        // 16,777,216
  unsigned short* vtg    = ybuf   + (size_t)2048 * 8192;        //  1,048,576
  unsigned short* kbuf   = vtg    + (size_t)512 * 2048;         //  1,179,648
  float*          lsumf  = (float*)(kbuf + (size_t)2048 * 576); //     32,768 floats
  // aliases:
  unsigned short* Ebuf   = ws;            // needs <= 18.36M shorts, have 20.45M (prefix thru lat)
  float*          P1     = (float*)qbuf;  // gemm1 partials: 13.6M shorts, have 18.9M
  float*          Pf     = (float*)ws;    // final partials: 33.6M shorts, have 39.3M (thru qbuf)

  prep_all<<<11360, 256, 0, stream>>>(x, xb, wqkv, wqkvT, wqdec, wqdecT, wout, woutT, lsumf);

  // latents = x @ W_qkv  (split-K x2 -> fp32 partials -> bf16 lat)
  gemm_splitk<<<dim3(13, 16, 2), 256, 0, stream>>>(xb, 2048, wqkvT, 2048, P1, 1664, 1024);
  reduce2_bf<<<3328, 256, 0, stream>>>(P1, lat, 2048 * 1664);
  rope_k<<<256, 256, 0, stream>>>(lat, kbuf, cosb, sinb);
  vtrans_kcopy<<<dim3(32, 8), 256, 0, stream>>>(lat, vtg, kbuf);

  // q = rope(c_q @ W_qdec)  -> bf16 [2048][9216], RoPE fused in epilogue
  gemm_qdec<<<dim3(72, 16), 256, 0, stream>>>(lat + 576, wqdecT, qbuf, cosb, sinb);

  // attention: 2 panels of q-tiles [0,11), [11,16); packed-causal E
  qke_kernel<<<dim3(66, 16), 256, 0, stream>>>(qbuf, kbuf, Ebuf, lsumf, 0, 11);
  pv_kernel<<<dim3(4, 11, 16), 256, 0, stream>>>(Ebuf, vtg, lsumf, ybuf, 0, 11);
  qke_kernel<<<dim3(70, 16), 256, 0, stream>>>(qbuf, kbuf, Ebuf, lsumf, 11, 16);
  pv_kernel<<<dim3(4, 5, 16), 256, 0, stream>>>(Ebuf, vtg, lsumf, ybuf, 11, 16);

  // out = y @ W_out  (split-K x4 -> fp32 partials -> fp32 out)
  gemm_splitk<<<dim3(16, 16, 4), 256, 0, stream>>>(ybuf, YLD, woutT, 8192, Pf, 2048, 2048);
  reduce4_f32<<<4096, 256, 0, stream>>>(Pf, out, 2048 * 2048);
}

// Round 6
// 505.542 us; speedup vs baseline: 3.1824x; 1.0776x over previous
//
#include <hip/hip_runtime.h>

typedef __bf16 bf16x8_t __attribute__((ext_vector_type(8)));
typedef float f32x4_t __attribute__((ext_vector_type(4)));

#define LAT_LD 1664
#define QK_DIM 576
#define V_DIM 512
#define NHEAD 16
#define TSEQ 2048
#define QLD 9216
#define YLD 8192
#define KLD 576
#define SCALE 0.044194173824159216f

__device__ __forceinline__ unsigned short f2bf(float f) {
  union { float f; unsigned int u; } v; v.f = f;
  unsigned int r = v.u + 0x7FFFu + ((v.u >> 16) & 1u);
  return (unsigned short)(r >> 16);
}

// async global->LDS 16B (m97 pattern). LDS dest must be wave-uniform base + lane*16.
__device__ __forceinline__ void load_lds16(const unsigned short* g, unsigned short* l) {
  __builtin_amdgcn_global_load_lds((const __attribute__((address_space(1))) void*)g,
                                   (__attribute__((address_space(3))) void*)l, 16, 0, 0);
}

// ---------------- fused prep: x->bf16, 3x transpose-convert, lsum zero ----------------
__device__ __forceinline__ void conv_t_body(const float* __restrict__ src, int R, int Csrc,
                                            unsigned short* __restrict__ dst,
                                            int bx, int by, int tid,
                                            unsigned short (*T)[72]) {
  const int r0 = bx * 64, c0 = by * 64;
  const bool live = (c0 < Csrc);
#pragma unroll
  for (int it = 0; it < 4; ++it) {
    int idx = it * 256 + tid;
    int r = idx >> 4, c4 = (idx & 15) * 4;   // row-contiguous: coalesced fp32 reads
    float4 v = {0.f, 0.f, 0.f, 0.f};
    if (live) v = *(const float4*)&src[(size_t)(r0 + r) * Csrc + c0 + c4];
    T[c4 + 0][r] = f2bf(v.x);
    T[c4 + 1][r] = f2bf(v.y);
    T[c4 + 2][r] = f2bf(v.z);
    T[c4 + 3][r] = f2bf(v.w);
  }
  __syncthreads();
#pragma unroll
  for (int it = 0; it < 2; ++it) {
    int idx = it * 256 + tid;
    int cc = idx >> 3, r8 = (idx & 7) * 8;
    uint4 v = *(const uint4*)&T[cc][r8];
    *(uint4*)&dst[(size_t)(c0 + cc) * R + r0 + r8] = v;
  }
}

// jobs: [0,4096) conv x; [4096,4928) wqkvT; [4928,7232) wqdecT; [7232,11328) woutT;
//       [11328,11360) zero lsum
__global__ __launch_bounds__(256) void prep_all(
    const float* __restrict__ x, unsigned short* __restrict__ xb,
    const float* __restrict__ wqkv, unsigned short* __restrict__ wqkvT,
    const float* __restrict__ wqdec, unsigned short* __restrict__ wqdecT,
    const float* __restrict__ wout, unsigned short* __restrict__ woutT,
    float* __restrict__ lsum) {
  __shared__ unsigned short T[64][72];
  const int blk = blockIdx.x, tid = threadIdx.x;
  if (blk < 4096) {
    int i = (blk * 256 + tid) * 4;
    float4 v = *(const float4*)&x[i];
    ushort4 o;
    o.x = f2bf(v.x); o.y = f2bf(v.y); o.z = f2bf(v.z); o.w = f2bf(v.w);
    *(ushort4*)&xb[i] = o;
  } else if (blk < 4928) {
    int l = blk - 4096;
    conv_t_body(wqkv, 2048, 1600, wqkvT, l & 31, l >> 5, tid, T);
  } else if (blk < 7232) {
    int l = blk - 4928;
    conv_t_body(wqdec, 1024, 9216, wqdecT, l & 15, l >> 4, tid, T);
  } else if (blk < 11328) {
    int l = blk - 7232;
    conv_t_body(wout, 8192, 2048, woutT, l & 127, l >> 7, tid, T);
  } else {
    int i = ((blk - 11328) * 256 + tid) * 4;
    *(float4*)&lsum[i] = (float4){0.f, 0.f, 0.f, 0.f};
  }
}

// ---------------- fused post-gemm1: reduce split-K partials + RoPE-K + V-transpose ----------------
// P1 = [2][2048][1664] fp32. Per 64x64 tile (bx=row-tile 0..31, by=col-tile 0..25):
//   by<8  : V region  -> kbuf row-major + vtg transposed
//   by==8 : rope cols 512..575 -> kbuf roped
//   by>8  : c_q -> lat row-major (cols 576..1663)
__global__ __launch_bounds__(256) void postlat(
    const float* __restrict__ P1,
    unsigned short* __restrict__ lat,
    unsigned short* __restrict__ kbuf,
    unsigned short* __restrict__ vtg,
    const float* __restrict__ cosb, const float* __restrict__ sinb) {
  __shared__ unsigned short T[64][72];
  const int tid = threadIdx.x;
  const int bx = blockIdx.x, by = blockIdx.y;
  const int r0 = bx * 64, c0 = by * 64;
  const size_t n = (size_t)2048 * 1664;

#pragma unroll
  for (int it = 0; it < 4; ++it) {
    int idx = it * 256 + tid;
    int r = idx >> 4, c4 = (idx & 15) * 4;
    size_t off = (size_t)(r0 + r) * 1664 + c0 + c4;
    float4 a = *(const float4*)&P1[off];
    float4 b = *(const float4*)&P1[n + off];
    ushort4 o;
    o.x = f2bf(a.x + b.x); o.y = f2bf(a.y + b.y);
    o.z = f2bf(a.z + b.z); o.w = f2bf(a.w + b.w);
    if (by < 8) {
      *(ushort4*)&kbuf[(size_t)(r0 + r) * KLD + c0 + c4] = o;
      T[c4 + 0][r] = o.x; T[c4 + 1][r] = o.y; T[c4 + 2][r] = o.z; T[c4 + 3][r] = o.w;
    } else if (by == 8) {
      T[r][c4 + 0] = o.x; T[r][c4 + 1] = o.y; T[r][c4 + 2] = o.z; T[r][c4 + 3] = o.w;
    } else {
      *(ushort4*)&lat[(size_t)(r0 + r) * LAT_LD + c0 + c4] = o;
    }
  }
  if (by > 8) return;
  __syncthreads();
  if (by < 8) {
    // vtg[c0+cc][r0..] from transposed tile
#pragma unroll
    for (int it = 0; it < 2; ++it) {
      int idx = it * 256 + tid;
      int cc = idx >> 3, r8 = (idx & 7) * 8;
      uint4 v = *(const uint4*)&T[cc][r8];
      *(uint4*)&vtg[(size_t)(c0 + cc) * TSEQ + r0 + r8] = v;
    }
  } else {
    // rope: pairs (d, d+32) within row
#pragma unroll
    for (int it = 0; it < 8; ++it) {
      int idx = it * 256 + tid;
      int r = idx >> 5, d = idx & 31;
      int t = r0 + r;
      union { unsigned int u; float f; } a, b;
      a.u = ((unsigned int)T[r][d]) << 16;
      b.u = ((unsigned int)T[r][d + 32]) << 16;
      float c0f = cosb[t * 64 + d], s0f = sinb[t * 64 + d];
      float c1f = cosb[t * 64 + d + 32], s1f = sinb[t * 64 + d + 32];
      kbuf[(size_t)t * KLD + 512 + d] = f2bf(a.f * c0f - b.f * s0f);
      kbuf[(size_t)t * KLD + 544 + d] = f2bf(b.f * c1f + a.f * s1f);
    }
  }
}

// ---------------- m97-style GEMM core, BK=64 (two 32-wide halves, proven layout) ----------------
#define GEMM_PROLOGUE()                                                     \
  __shared__ __align__(16) unsigned short As[8192];                         \
  __shared__ __align__(16) unsigned short Bs[8192];                         \
  const int tid = threadIdx.x;                                              \
  const int wave = tid >> 6, lane = tid & 63;                               \
  const int quad = lane >> 4, l16 = lane & 15;                              \
  const int wm = wave >> 1, wn = wave & 1;                                  \
  f32x4_t acc[4][4];                                                        \
  f32x4_t zero = {0.f, 0.f, 0.f, 0.f};                                      \
  _Pragma("unroll") for (int mi = 0; mi < 4; ++mi)                          \
    _Pragma("unroll") for (int ni = 0; ni < 4; ++ni) acc[mi][ni] = zero;

#define GEMM_KLOOP(Aptr, Alda, Bptr, Bldb, M0, N0, KLEN)                    \
  for (int k0 = 0; k0 < (KLEN); k0 += 64) {                                 \
    _Pragma("unroll") for (int p2 = 0; p2 < 2; ++p2) {                      \
      int ci = p2 * 256 + tid;                                              \
      int rr2 = ci >> 2, cc2 = (ci & 3) * 8;                                \
      const unsigned short* ga = &(Aptr)[(size_t)((M0) + rr2) * (Alda) + k0 + cc2]; \
      const unsigned short* gb = &(Bptr)[(size_t)((N0) + rr2) * (Bldb) + k0 + cc2]; \
      load_lds16(ga,      &As[ci * 8]);                                     \
      load_lds16(ga + 32, &As[4096 + ci * 8]);                              \
      load_lds16(gb,      &Bs[ci * 8]);                                     \
      load_lds16(gb + 32, &Bs[4096 + ci * 8]);                              \
    }                                                                       \
    __syncthreads();                                                        \
    _Pragma("unroll") for (int hf = 0; hf < 2; ++hf) {                      \
      bf16x8_t af[4], bfr[4];                                               \
      _Pragma("unroll") for (int mi = 0; mi < 4; ++mi)                      \
        af[mi] = *(const bf16x8_t*)&As[hf * 4096 + (wm * 64 + mi * 16 + l16) * 32 + quad * 8]; \
      _Pragma("unroll") for (int ni = 0; ni < 4; ++ni)                      \
        bfr[ni] = *(const bf16x8_t*)&Bs[hf * 4096 + (wn * 64 + ni * 16 + l16) * 32 + quad * 8]; \
      _Pragma("unroll") for (int mi = 0; mi < 4; ++mi)                      \
        _Pragma("unroll") for (int ni = 0; ni < 4; ++ni)                    \
          acc[mi][ni] = __builtin_amdgcn_mfma_f32_16x16x32_bf16(af[mi], bfr[ni], acc[mi][ni], 0, 0, 0); \
    }                                                                       \
    __syncthreads();                                                        \
  }

// ---------------- split-K GEMM: P[s][M][N] fp32 partials, slice K = Ks ----------------
__global__ __launch_bounds__(256, 2) void gemm_splitk(
    const unsigned short* __restrict__ A, int lda,
    const unsigned short* __restrict__ Bt, int ldb,
    float* __restrict__ P, int ldc, int Ks) {
  const int m0 = blockIdx.y * 128, n0 = blockIdx.x * 128;
  const size_t koff = (size_t)blockIdx.z * Ks;
  const unsigned short* Ap = A + koff;
  const unsigned short* Bp = Bt + koff;
  float* C = P + (size_t)blockIdx.z * ((size_t)gridDim.y * 128) * ldc;
  GEMM_PROLOGUE();
  GEMM_KLOOP(Ap, lda, Bp, ldb, m0, n0, Ks);
#pragma unroll
  for (int mi = 0; mi < 4; ++mi)
#pragma unroll
    for (int ni = 0; ni < 4; ++ni)
#pragma unroll
      for (int r = 0; r < 4; ++r) {
        int row = m0 + wm * 64 + mi * 16 + quad * 4 + r;
        int col = n0 + wn * 64 + ni * 16 + l16;
        C[(size_t)row * ldc + col] = acc[mi][ni][r];
      }
}

// ---------------- gemm2 with fused RoPE-q epilogue: qbuf = rope(c_q @ W_qdec) ----------------
__global__ __launch_bounds__(256, 2) void gemm_qdec(
    const unsigned short* __restrict__ A,      // lat + 576 (c_q), lda LAT_LD
    const unsigned short* __restrict__ Bt,     // wqdecT [9216][1024]
    unsigned short* __restrict__ qbuf,
    const float* __restrict__ cosb, const float* __restrict__ sinb) {
  const int m0 = blockIdx.y * 128, n0 = blockIdx.x * 128;
  GEMM_PROLOGUE();
  GEMM_KLOOP(A, LAT_LD, Bt, 1024, m0, n0, 1024);

  const int cb = n0 + wn * 64;                 // this wave's 64-col half
  const bool ropeh = (cb % QK_DIM) == 512;     // rope region is 64-aligned, 64 wide
#pragma unroll
  for (int mi = 0; mi < 4; ++mi)
#pragma unroll
    for (int r = 0; r < 4; ++r) {
      int t = m0 + wm * 64 + mi * 16 + quad * 4 + r;
      if (ropeh) {
#pragma unroll
        for (int ni = 0; ni < 2; ++ni) {
          int d = ni * 16 + l16;
          float c0f = cosb[t * 64 + d], s0f = sinb[t * 64 + d];
          float c1f = cosb[t * 64 + d + 32], s1f = sinb[t * 64 + d + 32];
          float v1 = acc[mi][ni][r], v2 = acc[mi][ni + 2][r];
          qbuf[(size_t)t * QLD + cb + d] = f2bf(v1 * c0f - v2 * s0f);
          qbuf[(size_t)t * QLD + cb + 32 + d] = f2bf(v2 * c1f + v1 * s1f);
        }
      } else {
#pragma unroll
        for (int ni = 0; ni < 4; ++ni)
          qbuf[(size_t)t * QLD + cb + ni * 16 + l16] = f2bf(acc[mi][ni][r]);
      }
    }
}

// ---------------- split-K reduction (final) ----------------
__global__ __launch_bounds__(256) void reduce4_f32(const float* __restrict__ p,
                                                   float* __restrict__ dst, int n) {
  int i = (blockIdx.x * 256 + threadIdx.x) * 4;
  if (i < n) {
    float4 a = *(const float4*)&p[i];
    float4 b = *(const float4*)&p[(size_t)n + i];
    float4 c = *(const float4*)&p[2 * (size_t)n + i];
    float4 d = *(const float4*)&p[3 * (size_t)n + i];
    float4 o;
    o.x = (a.x + b.x) + (c.x + d.x);
    o.y = (a.y + b.y) + (c.y + d.y);
    o.z = (a.z + b.z) + (c.z + d.z);
    o.w = (a.w + b.w) + (c.w + d.w);
    *(float4*)&dst[i] = o;
  }
}

// ---------------- QK^T + exp pass for 8 heads, all 16 q-tiles, packed-causal E ----------------
// E per head: tiles ig=0..15, tile ig has 128 rows x (ig+1)*128 cols, packed; head-local
// stride 136*16384 shorts. grid: (136, 8), heavy q-tiles first.
__global__ __launch_bounds__(256, 2) void qke_kernel(
    const unsigned short* __restrict__ qbuf,
    const unsigned short* __restrict__ kbuf,
    unsigned short* __restrict__ Ebuf,
    float* __restrict__ lsum, int hbase) {
  int tx = blockIdx.x, ig = 15, cnt = 16;
  while (tx >= cnt) { tx -= cnt; --ig; --cnt; }
  const int j = tx;                       // key tile
  const int hl = blockIdx.y, h = hbase + hl;
  const int Kmax = (ig + 1) << 7;
  const int r0g = ig << 7;
  const int pre = (ig * (ig + 1)) >> 1;

  const unsigned short* A = qbuf + (size_t)r0g * QLD + h * QK_DIM;
  const unsigned short* Bt = kbuf + (size_t)(j << 7) * KLD;
  unsigned short* Eh = Ebuf + ((size_t)hl * 136 + pre) * 16384;

  GEMM_PROLOGUE();
  GEMM_KLOOP(A, QLD, Bt, KLD, 0, 0, QK_DIM);

#pragma unroll
  for (int mi = 0; mi < 4; ++mi) {
    float rs[4] = {0.f, 0.f, 0.f, 0.f};
#pragma unroll
    for (int ni = 0; ni < 4; ++ni)
#pragma unroll
      for (int r = 0; r < 4; ++r) {
        int qr = r0g + wm * 64 + mi * 16 + quad * 4 + r;
        int key = (j << 7) + wn * 64 + ni * 16 + l16;
        float e = (key <= qr) ? __expf(acc[mi][ni][r] * SCALE) : 0.f;
        rs[r] += e;
        Eh[(size_t)(qr - r0g) * Kmax + key] = f2bf(e);
      }
#pragma unroll
    for (int r = 0; r < 4; ++r) {
      float s = rs[r];
#pragma unroll
      for (int off = 1; off < 16; off <<= 1) s += __shfl_xor(s, off, 64);
      if (l16 == 0) {
        int qr = r0g + wm * 64 + mi * 16 + quad * 4 + r;
        atomicAdd(&lsum[h * TSEQ + qr], s);
      }
    }
  }
}

// ---------------- PV pass: y = (E @ V) / rowsum ----------------
// grid: (4 n-tiles, 16 q-tiles heavy-first, 8 heads)
__global__ __launch_bounds__(256, 2) void pv_kernel(
    const unsigned short* __restrict__ Ebuf,
    const unsigned short* __restrict__ vtg,
    const float* __restrict__ lsum,
    unsigned short* __restrict__ ybuf, int hbase) {
  const int ig = 15 - blockIdx.y;          // heavy first
  const int hl = blockIdx.z, h = hbase + hl;
  const int n0 = blockIdx.x * 128;
  const int Kmax = (ig + 1) << 7;
  const int pre = (ig * (ig + 1)) >> 1;

  const unsigned short* A = Ebuf + ((size_t)hl * 136 + pre) * 16384;

  GEMM_PROLOGUE();
  GEMM_KLOOP(A, Kmax, vtg, TSEQ, 0, n0, Kmax);

#pragma unroll
  for (int mi = 0; mi < 4; ++mi)
#pragma unroll
    for (int r = 0; r < 4; ++r) {
      int row_g = (ig << 7) + wm * 64 + mi * 16 + quad * 4 + r;
      float inv = 1.f / lsum[h * TSEQ + row_g];
#pragma unroll
      for (int ni = 0; ni < 4; ++ni) {
        int col = h * V_DIM + n0 + wn * 64 + ni * 16 + l16;
        ybuf[(size_t)row_g * YLD + col] = f2bf(acc[mi][ni][r] * inv);
      }
    }
}

// ---------------- launch ----------------
extern "C" void kernel_launch(void* const* d_in, const int* in_sizes, int n_in,
                              void* d_out, int out_size, void* d_ws, size_t ws_size,
                              hipStream_t stream) {
  (void)in_sizes; (void)n_in; (void)out_size; (void)ws_size;
  const float* x     = (const float*)d_in[0];
  const float* cosb  = (const float*)d_in[1];
  const float* sinb  = (const float*)d_in[2];
  const float* wqkv  = (const float*)d_in[3];
  const float* wqdec = (const float*)d_in[4];
  const float* wout  = (const float*)d_in[5];
  float* out = (float*)d_out;

  // ws layout (shorts). [xb, wqkvT, wqdecT, lat] dead by attention time -> Ebuf alias.
  unsigned short* ws     = (unsigned short*)d_ws;
  unsigned short* xb     = ws;                                  //  4,194,304
  unsigned short* wqkvT  = xb     + (size_t)2048 * 2048;        //  3,407,872
  unsigned short* wqdecT = wqkvT  + (size_t)1664 * 2048;        //  9,437,184
  unsigned short* lat    = wqdecT + (size_t)9216 * 1024;        //  3,407,872  (ends 20,447,232)
  unsigned short* qbuf   = lat    + (size_t)2048 * 1664;        // 18,874,368  (ends 39,321,600)
  unsigned short* woutT  = qbuf   + (size_t)2048 * 9216;        // 16,777,216
  unsigned short* ybuf   = woutT  + (size_t)2048 * 8192;        // 16,777,216
  unsigned short* vtg    = ybuf   + (size_t)2048 * 8192;        //  1,048,576
  unsigned short* kbuf   = vtg    + (size_t)512 * 2048;         //  1,179,648
  float*          lsumf  = (float*)(kbuf + (size_t)2048 * 576); //     32,768 floats
  // aliases:
  unsigned short* Ebuf   = ws;            // 8 heads x 136 tiles x 16384 = 17.83M shorts <= 20.45M
  float*          P1     = (float*)qbuf;  // gemm1 partials: 6.82M floats <= 9.44M
  float*          Pf     = (float*)ws;    // final partials: 16.78M floats <= 19.66M (thru qbuf)

  prep_all<<<11360, 256, 0, stream>>>(x, xb, wqkv, wqkvT, wqdec, wqdecT, wout, woutT, lsumf);

  // latents = x @ W_qkv  (split-K x2 -> fp32 partials)
  gemm_splitk<<<dim3(13, 16, 2), 256, 0, stream>>>(xb, 2048, wqkvT, 2048, P1, 1664, 1024);
  // fused: reduce partials + RoPE-K -> kbuf, V-transpose -> vtg, c_q -> lat
  postlat<<<dim3(32, 26), 256, 0, stream>>>(P1, lat, kbuf, vtg, cosb, sinb);

  // q = rope(c_q @ W_qdec)  -> bf16 [2048][9216], RoPE fused in epilogue
  gemm_qdec<<<dim3(72, 16), 256, 0, stream>>>(lat + 576, wqdecT, qbuf, cosb, sinb);

  // attention: 2 head-panels of 8 heads each; packed-causal E
  qke_kernel<<<dim3(136, 8), 256, 0, stream>>>(qbuf, kbuf, Ebuf, lsumf, 0);
  pv_kernel<<<dim3(4, 16, 8), 256, 0, stream>>>(Ebuf, vtg, lsumf, ybuf, 0);
  qke_kernel<<<dim3(136, 8), 256, 0, stream>>>(qbuf, kbuf, Ebuf, lsumf, 8);
  pv_kernel<<<dim3(4, 16, 8), 256, 0, stream>>>(Ebuf, vtg, lsumf, ybuf, 8);

  // out = y @ W_out  (split-K x4 -> fp32 partials -> fp32 out)
  gemm_splitk<<<dim3(16, 16, 4), 256, 0, stream>>>(ybuf, YLD, woutT, 8192, Pf, 2048, 2048);
  reduce4_f32<<<4096, 256, 0, stream>>>(Pf, out, 2048 * 2048);
}